// Round 1
// baseline (1050.545 us; speedup 1.0000x reference)
//
#include <hip/hip_runtime.h>

#define N_F     64
#define N_REL   32
#define N_BASES 30
#define CHUNK   4096
#define BLOCK   256

// ---------------------------------------------------------------------------
// K1: relation weights W[r][i][o] = sum_b coeff[r][b] * basis[b][i][o]
// ---------------------------------------------------------------------------
__global__ void k_relw(const float* __restrict__ basis,
                       const float* __restrict__ coeff,
                       float* __restrict__ W) {
    int idx = blockIdx.x * blockDim.x + threadIdx.x;   // 32 * 4096 threads
    if (idx >= N_REL * N_F * N_F) return;
    int r  = idx >> 12;           // / 4096
    int io = idx & 4095;
    float acc = 0.f;
#pragma unroll
    for (int b = 0; b < N_BASES; ++b)
        acc += coeff[r * N_BASES + b] * basis[b * (N_F * N_F) + io];
    W[idx] = acc;
}

// ---------------------------------------------------------------------------
// K2: in-degree (int atomics, native HW path)
// ---------------------------------------------------------------------------
__global__ void k_deg(const int* __restrict__ recv, int* __restrict__ deg, int E) {
    int e = blockIdx.x * blockDim.x + threadIdx.x;
    if (e < E) atomicAdd(&deg[recv[e]], 1);
}

// ---------------------------------------------------------------------------
// K3: main edge kernel.
// grid = (num_chunks, N_REL). Block (c, r): stage W_r in LDS, scan chunk c for
// edges with rel==r into an LDS queue, then process: 4 edges per wave,
// 16 lanes per edge, 4 outputs per lane. Scatter-add into out via
// global_atomic_add_f32 (unsafeAtomicAdd).
// ---------------------------------------------------------------------------
__global__ void k_edges(const float* __restrict__ nf,
                        const int*   __restrict__ snd,
                        const int*   __restrict__ rcv,
                        const int*   __restrict__ rel,
                        const float* __restrict__ W,
                        float*       __restrict__ out,
                        int E) {
    __shared__ float sW[N_F * N_F];     // 16 KB, row-major [i][o]
    __shared__ int   s_queue[CHUNK];    // 16 KB
    __shared__ int   s_cnt;

    const int tid  = threadIdx.x;
    const int r    = blockIdx.y;
    const int base = blockIdx.x * CHUNK;
    const int len  = min(CHUNK, E - base);

    if (tid == 0) s_cnt = 0;

    // stage W_r (coalesced float4 copy; LDS layout == global layout)
    {
        const float4* Wg4 = (const float4*)(W + r * (N_F * N_F));
        float4* sW4 = (float4*)sW;
#pragma unroll
        for (int i = tid; i < (N_F * N_F / 4); i += BLOCK) sW4[i] = Wg4[i];
    }
    __syncthreads();   // covers s_cnt init

    // scan chunk, build match queue (cannot overflow: matches <= len <= CHUNK)
    for (int t = tid; t < len; t += BLOCK) {
        if (rel[base + t] == r) {
            int p = atomicAdd(&s_cnt, 1);
            s_queue[p] = t;
        }
    }
    __syncthreads();
    const int cnt = s_cnt;

    const int lane = tid & 63;
    const int wave = tid >> 6;     // 4 waves
    const int sub  = lane >> 4;    // edge within group of 4
    const int og   = lane & 15;    // output group: cols 4*og .. 4*og+3

    const float4* sW4 = (const float4*)sW;   // [i][og] float4 view

    for (int qb = wave * 4; qb < cnt; qb += 16) {
        int  q     = qb + sub;
        bool valid = q < cnt;
        int  e     = base + s_queue[valid ? q : cnt - 1];
        int  s     = snd[e];
        int  d     = rcv[e];
        const float* xr = nf + (size_t)s * N_F;

        float ay0 = 0.f, ay1 = 0.f, ay2 = 0.f, ay3 = 0.f;
#pragma unroll
        for (int i = 0; i < N_F; i += 4) {
            float4 xv = *(const float4*)(xr + i);      // same addr across 16 lanes
            float4 w0 = sW4[(i + 0) * 16 + og];
            float4 w1 = sW4[(i + 1) * 16 + og];
            float4 w2 = sW4[(i + 2) * 16 + og];
            float4 w3 = sW4[(i + 3) * 16 + og];
            ay0 += xv.x * w0.x + xv.y * w1.x + xv.z * w2.x + xv.w * w3.x;
            ay1 += xv.x * w0.y + xv.y * w1.y + xv.z * w2.y + xv.w * w3.y;
            ay2 += xv.x * w0.z + xv.y * w1.z + xv.z * w2.z + xv.w * w3.z;
            ay3 += xv.x * w0.w + xv.y * w1.w + xv.z * w2.w + xv.w * w3.w;
        }
        if (valid) {
            float* op = out + (size_t)d * N_F + og * 4;
            unsafeAtomicAdd(op + 0, ay0);
            unsafeAtomicAdd(op + 1, ay1);
            unsafeAtomicAdd(op + 2, ay2);
            unsafeAtomicAdd(op + 3, ay3);
        }
    }
}

// ---------------------------------------------------------------------------
// K4: out[n] = out[n] / max(deg,1) + nf[n] @ self_weight + bias
// 4 nodes per wave (16 lanes / node, 4 outputs / lane), self_weight in LDS.
// ---------------------------------------------------------------------------
__global__ void k_final(const float* __restrict__ nf,
                        const float* __restrict__ sw,
                        const float* __restrict__ bias,
                        const int*   __restrict__ deg,
                        float*       __restrict__ out,
                        int N) {
    __shared__ float sW[N_F * N_F];
    const int tid = threadIdx.x;
    {
        const float4* swg = (const float4*)sw;
        float4* sW4 = (float4*)sW;
#pragma unroll
        for (int i = tid; i < (N_F * N_F / 4); i += BLOCK) sW4[i] = swg[i];
    }
    __syncthreads();

    const int lane = tid & 63;
    const int wave = tid >> 6;
    const int sub  = lane >> 4;
    const int og   = lane & 15;

    int n = (blockIdx.x * 4 + wave) * 4 + sub;
    if (n >= N) return;

    const float* xr = nf + (size_t)n * N_F;
    const float4* sW4 = (const float4*)sW;

    float ay0 = 0.f, ay1 = 0.f, ay2 = 0.f, ay3 = 0.f;
#pragma unroll
    for (int i = 0; i < N_F; i += 4) {
        float4 xv = *(const float4*)(xr + i);
        float4 w0 = sW4[(i + 0) * 16 + og];
        float4 w1 = sW4[(i + 1) * 16 + og];
        float4 w2 = sW4[(i + 2) * 16 + og];
        float4 w3 = sW4[(i + 3) * 16 + og];
        ay0 += xv.x * w0.x + xv.y * w1.x + xv.z * w2.x + xv.w * w3.x;
        ay1 += xv.x * w0.y + xv.y * w1.y + xv.z * w2.y + xv.w * w3.y;
        ay2 += xv.x * w0.z + xv.y * w1.z + xv.z * w2.z + xv.w * w3.z;
        ay3 += xv.x * w0.w + xv.y * w1.w + xv.z * w2.w + xv.w * w3.w;
    }

    float dg = (float)deg[n];
    dg = dg < 1.f ? 1.f : dg;
    float inv = 1.f / dg;

    float4 b4 = ((const float4*)bias)[og];
    float* op = out + (size_t)n * N_F + og * 4;
    float4 prev = *(const float4*)op;
    op[0] = prev.x * inv + ay0 + b4.x;
    op[1] = prev.y * inv + ay1 + b4.y;
    op[2] = prev.z * inv + ay2 + b4.z;
    op[3] = prev.w * inv + ay3 + b4.w;
}

// ---------------------------------------------------------------------------
extern "C" void kernel_launch(void* const* d_in, const int* in_sizes, int n_in,
                              void* d_out, int out_size, void* d_ws, size_t ws_size,
                              hipStream_t stream) {
    const float* nf    = (const float*)d_in[0];
    const int*   snd   = (const int*)  d_in[1];
    const int*   rcv   = (const int*)  d_in[2];
    const int*   rel   = (const int*)  d_in[3];
    const float* basis = (const float*)d_in[4];
    const float* coeff = (const float*)d_in[5];
    const float* selfw = (const float*)d_in[6];
    const float* bias  = (const float*)d_in[7];
    float*       out   = (float*)d_out;

    const int N = in_sizes[0] / N_F;
    const int E = in_sizes[1];

    float* W   = (float*)d_ws;                                       // 512 KB
    int*   deg = (int*)((char*)d_ws + (size_t)N_REL * N_F * N_F * 4); // N ints

    hipMemsetAsync(d_out, 0, (size_t)N * N_F * sizeof(float), stream);
    hipMemsetAsync(deg, 0, (size_t)N * sizeof(int), stream);

    k_relw<<<(N_REL * N_F * N_F + BLOCK - 1) / BLOCK, BLOCK, 0, stream>>>(basis, coeff, W);
    k_deg<<<(E + BLOCK - 1) / BLOCK, BLOCK, 0, stream>>>(rcv, deg, E);

    int chunks = (E + CHUNK - 1) / CHUNK;
    dim3 g3(chunks, N_REL);
    k_edges<<<g3, BLOCK, 0, stream>>>(nf, snd, rcv, rel, W, out, E);

    int ngroups = (N + 3) / 4;            // wave-groups of 4 nodes
    int blocks4 = (ngroups + 3) / 4;      // 4 waves / block
    k_final<<<blocks4, BLOCK, 0, stream>>>(nf, selfw, bias, deg, out, N);
}

// Round 2
// 1000.822 us; speedup vs baseline: 1.0497x; 1.0497x over previous
//
#include <hip/hip_runtime.h>

#define N_F     64
#define N_REL   32
#define BLOCK   256
#define RPB     128          // receivers per k_main block (must be pow2)
#define SCAN_TILE 2048       // bins per scan tile

// ---------------------------------------------------------------------------
// K1: relation weights W[r][i][o] = sum_b coeff[r][b] * basis[b][i][o]
// ---------------------------------------------------------------------------
__global__ void k_relw(const float* __restrict__ basis,
                       const float* __restrict__ coeff,
                       float* __restrict__ W) {
    int idx = blockIdx.x * blockDim.x + threadIdx.x;
    if (idx >= N_REL * N_F * N_F) return;
    int r  = idx >> 12;
    int io = idx & 4095;
    float acc = 0.f;
#pragma unroll
    for (int b = 0; b < 30; ++b)
        acc += coeff[r * 30 + b] * basis[b * (N_F * N_F) + io];
    W[idx] = acc;
}

// ---------------------------------------------------------------------------
// K2: in-degree (int atomics)
// ---------------------------------------------------------------------------
__global__ void k_deg(const int* __restrict__ recv, int* __restrict__ deg, int E) {
    int e = blockIdx.x * blockDim.x + threadIdx.x;
    if (e < E) atomicAdd(&deg[recv[e]], 1);
}

// ---------------------------------------------------------------------------
// Counting sort by key = rel*N + recv
// ---------------------------------------------------------------------------
__global__ void k_hist(const int* __restrict__ rcv, const int* __restrict__ rel,
                       int* __restrict__ cur, int E, int N) {
    int e = blockIdx.x * blockDim.x + threadIdx.x;
    if (e < E) atomicAdd(&cur[rel[e] * N + rcv[e]], 1);
}

// T1: per-tile sums
__global__ void k_scan_sums(const int* __restrict__ cur, int* __restrict__ part,
                            int nbins) {
    __shared__ int red[BLOCK];
    int base = blockIdx.x * SCAN_TILE;
    int s = 0;
    for (int i = threadIdx.x; i < SCAN_TILE; i += BLOCK) {
        int idx = base + i;
        s += (idx < nbins) ? cur[idx] : 0;
    }
    red[threadIdx.x] = s;
    __syncthreads();
    for (int off = BLOCK / 2; off > 0; off >>= 1) {
        if (threadIdx.x < off) red[threadIdx.x] += red[threadIdx.x + off];
        __syncthreads();
    }
    if (threadIdx.x == 0) part[blockIdx.x] = red[0];
}

// T2: single-block exclusive scan of tile sums (in place)
__global__ void k_scan_part(int* __restrict__ part, int npart) {
    __shared__ int buf[BLOCK];
    __shared__ int carry;
    if (threadIdx.x == 0) carry = 0;
    __syncthreads();
    int nchunk = (npart + BLOCK - 1) / BLOCK;
    for (int c = 0; c < nchunk; ++c) {
        int i = c * BLOCK + threadIdx.x;
        int v = (i < npart) ? part[i] : 0;
        buf[threadIdx.x] = v;
        __syncthreads();
        for (int off = 1; off < BLOCK; off <<= 1) {
            int t = (threadIdx.x >= off) ? buf[threadIdx.x - off] : 0;
            __syncthreads();
            buf[threadIdx.x] += t;
            __syncthreads();
        }
        int incl = buf[threadIdx.x];
        int excl = incl - v + carry;          // carry read before update barrier
        if (i < npart) part[i] = excl;
        int chunk_sum = buf[BLOCK - 1];
        __syncthreads();
        if (threadIdx.x == 0) carry += chunk_sum;
        __syncthreads();
    }
}

// T3: per-tile exclusive scan + tile offset, in place
__global__ void k_scan_apply(int* __restrict__ cur, const int* __restrict__ part,
                             int nbins) {
    __shared__ int buf[BLOCK];
    int base_t = blockIdx.x * SCAN_TILE + threadIdx.x * 8;
    int loc[8];
    int s = 0;
#pragma unroll
    for (int j = 0; j < 8; ++j) {
        int idx = base_t + j;
        int v = (idx < nbins) ? cur[idx] : 0;
        loc[j] = s;
        s += v;
    }
    buf[threadIdx.x] = s;
    __syncthreads();
    for (int off = 1; off < BLOCK; off <<= 1) {
        int t = (threadIdx.x >= off) ? buf[threadIdx.x - off] : 0;
        __syncthreads();
        buf[threadIdx.x] += t;
        __syncthreads();
    }
    int excl = buf[threadIdx.x] - s + part[blockIdx.x];
#pragma unroll
    for (int j = 0; j < 8; ++j) {
        int idx = base_t + j;
        if (idx < nbins) cur[idx] = loc[j] + excl;
    }
}

// scatter: after this, cur[k] == binptr[k+1] (end pointer of bin k)
__global__ void k_scatter(const int* __restrict__ snd, const int* __restrict__ rcv,
                          const int* __restrict__ rel, int* __restrict__ cur,
                          int* __restrict__ epack, int E, int N) {
    int e = blockIdx.x * blockDim.x + threadIdx.x;
    if (e < E) {
        int d = rcv[e];
        int pos = atomicAdd(&cur[rel[e] * N + d], 1);
        epack[pos] = snd[e] | ((d & (RPB - 1)) << 17);
    }
}

// ---------------------------------------------------------------------------
// K-main: block owns 128 receivers; y accumulators in LDS; loop over 32 rels
// staging W_r in LDS; edges for (rel, recv-block) are a contiguous sorted
// slice. LDS float atomics for y; single coalesced out write. No global
// float atomics.
// ---------------------------------------------------------------------------
__global__ void __launch_bounds__(BLOCK) k_main(const float* __restrict__ nf,
                                                const int*   __restrict__ epack,
                                                const int*   __restrict__ cur,
                                                const float* __restrict__ W,
                                                float*       __restrict__ out,
                                                int N) {
    __shared__ float sW[N_F * N_F];      // 16 KB
    __shared__ float sy[RPB * N_F];      // 32 KB

    const int tid = threadIdx.x;
    const int nb0 = blockIdx.x * RPB;
    const int len = min(RPB, N - nb0);

    float4* sy4 = (float4*)sy;
    for (int i = tid; i < RPB * N_F / 4; i += BLOCK)
        sy4[i] = float4{0.f, 0.f, 0.f, 0.f};

    const int lane = tid & 63;
    const int wave = tid >> 6;
    const int sub  = lane >> 4;
    const int og   = lane & 15;
    const float4* sW4 = (const float4*)sW;

    for (int r = 0; r < N_REL; ++r) {
        __syncthreads();   // protects sW overwrite (and sy zero at r=0)
        {
            const float4* Wg4 = (const float4*)(W + r * (N_F * N_F));
            float4* sWw = (float4*)sW;
#pragma unroll
            for (int i = tid; i < (N_F * N_F / 4); i += BLOCK) sWw[i] = Wg4[i];
        }
        __syncthreads();

        const int idx   = r * N + nb0;
        const int start = (idx == 0) ? 0 : cur[idx - 1];
        const int end   = cur[idx + len - 1];

        for (int eb = start + wave * 4; eb < end; eb += 16) {
            int  e     = eb + sub;
            bool valid = e < end;
            int  ep    = epack[valid ? e : end - 1];
            int  s     = ep & 0x1FFFF;
            int  rl    = (ep >> 17) & (RPB - 1);
            const float* xr = nf + (size_t)s * N_F;

            float ay0 = 0.f, ay1 = 0.f, ay2 = 0.f, ay3 = 0.f;
#pragma unroll
            for (int i = 0; i < N_F; i += 4) {
                float4 xv = *(const float4*)(xr + i);
                float4 w0 = sW4[(i + 0) * 16 + og];
                float4 w1 = sW4[(i + 1) * 16 + og];
                float4 w2 = sW4[(i + 2) * 16 + og];
                float4 w3 = sW4[(i + 3) * 16 + og];
                ay0 += xv.x * w0.x + xv.y * w1.x + xv.z * w2.x + xv.w * w3.x;
                ay1 += xv.x * w0.y + xv.y * w1.y + xv.z * w2.y + xv.w * w3.y;
                ay2 += xv.x * w0.z + xv.y * w1.z + xv.z * w2.z + xv.w * w3.z;
                ay3 += xv.x * w0.w + xv.y * w1.w + xv.z * w2.w + xv.w * w3.w;
            }
            if (valid) {
                float* yp = &sy[rl * N_F + og * 4];
                unsafeAtomicAdd(yp + 0, ay0);
                unsafeAtomicAdd(yp + 1, ay1);
                unsafeAtomicAdd(yp + 2, ay2);
                unsafeAtomicAdd(yp + 3, ay3);
            }
        }
    }
    __syncthreads();

    float4* og4 = (float4*)(out + (size_t)nb0 * N_F);
    for (int i = tid; i < len * N_F / 4; i += BLOCK)
        og4[i] = sy4[i];
}

// ---------------------------------------------------------------------------
// K-final: out = out/max(deg,1) + nf @ self_weight + bias
// ---------------------------------------------------------------------------
__global__ void k_final(const float* __restrict__ nf,
                        const float* __restrict__ sw,
                        const float* __restrict__ bias,
                        const int*   __restrict__ deg,
                        float*       __restrict__ out,
                        int N) {
    __shared__ float sW[N_F * N_F];
    const int tid = threadIdx.x;
    {
        const float4* swg = (const float4*)sw;
        float4* sW4 = (float4*)sW;
#pragma unroll
        for (int i = tid; i < (N_F * N_F / 4); i += BLOCK) sW4[i] = swg[i];
    }
    __syncthreads();

    const int lane = tid & 63;
    const int wave = tid >> 6;
    const int sub  = lane >> 4;
    const int og   = lane & 15;

    int n = (blockIdx.x * 4 + wave) * 4 + sub;
    if (n >= N) return;

    const float* xr = nf + (size_t)n * N_F;
    const float4* sW4 = (const float4*)sW;

    float ay0 = 0.f, ay1 = 0.f, ay2 = 0.f, ay3 = 0.f;
#pragma unroll
    for (int i = 0; i < N_F; i += 4) {
        float4 xv = *(const float4*)(xr + i);
        float4 w0 = sW4[(i + 0) * 16 + og];
        float4 w1 = sW4[(i + 1) * 16 + og];
        float4 w2 = sW4[(i + 2) * 16 + og];
        float4 w3 = sW4[(i + 3) * 16 + og];
        ay0 += xv.x * w0.x + xv.y * w1.x + xv.z * w2.x + xv.w * w3.x;
        ay1 += xv.x * w0.y + xv.y * w1.y + xv.z * w2.y + xv.w * w3.y;
        ay2 += xv.x * w0.z + xv.y * w1.z + xv.z * w2.z + xv.w * w3.z;
        ay3 += xv.x * w0.w + xv.y * w1.w + xv.z * w2.w + xv.w * w3.w;
    }

    float dg = (float)deg[n];
    dg = dg < 1.f ? 1.f : dg;
    float inv = 1.f / dg;

    float4 b4 = ((const float4*)bias)[og];
    float* op = out + (size_t)n * N_F + og * 4;
    float4 prev = *(const float4*)op;
    op[0] = prev.x * inv + ay0 + b4.x;
    op[1] = prev.y * inv + ay1 + b4.y;
    op[2] = prev.z * inv + ay2 + b4.z;
    op[3] = prev.w * inv + ay3 + b4.w;
}

// ---------------------------------------------------------------------------
extern "C" void kernel_launch(void* const* d_in, const int* in_sizes, int n_in,
                              void* d_out, int out_size, void* d_ws, size_t ws_size,
                              hipStream_t stream) {
    const float* nf    = (const float*)d_in[0];
    const int*   snd   = (const int*)  d_in[1];
    const int*   rcv   = (const int*)  d_in[2];
    const int*   rel   = (const int*)  d_in[3];
    const float* basis = (const float*)d_in[4];
    const float* coeff = (const float*)d_in[5];
    const float* selfw = (const float*)d_in[6];
    const float* bias  = (const float*)d_in[7];
    float*       out   = (float*)d_out;

    const int N = in_sizes[0] / N_F;    // 100000
    const int E = in_sizes[1];          // 1000000
    const int NBINS = N_REL * N;        // 3.2M
    const int NPART = (NBINS + SCAN_TILE - 1) / SCAN_TILE;

    // ws layout: W | deg | cur(bins) | part | epack  (~17.7 MB total)
    float* W     = (float*)d_ws;
    int*   deg   = (int*)(W + N_REL * N_F * N_F);
    int*   cur   = deg + N;
    int*   part  = cur + NBINS;
    int*   epack = part + NPART;

    hipMemsetAsync(deg, 0, (size_t)N * sizeof(int), stream);
    hipMemsetAsync(cur, 0, (size_t)NBINS * sizeof(int), stream);

    k_relw<<<(N_REL * N_F * N_F + BLOCK - 1) / BLOCK, BLOCK, 0, stream>>>(basis, coeff, W);
    k_deg <<<(E + BLOCK - 1) / BLOCK, BLOCK, 0, stream>>>(rcv, deg, E);
    k_hist<<<(E + BLOCK - 1) / BLOCK, BLOCK, 0, stream>>>(rcv, rel, cur, E, N);
    k_scan_sums <<<NPART, BLOCK, 0, stream>>>(cur, part, NBINS);
    k_scan_part <<<1,     BLOCK, 0, stream>>>(part, NPART);
    k_scan_apply<<<NPART, BLOCK, 0, stream>>>(cur, part, NBINS);
    k_scatter<<<(E + BLOCK - 1) / BLOCK, BLOCK, 0, stream>>>(snd, rcv, rel, cur, epack, E, N);

    int nblocks = (N + RPB - 1) / RPB;
    k_main<<<nblocks, BLOCK, 0, stream>>>(nf, epack, cur, W, out, N);

    int ngroups = (N + 3) / 4;
    int blocks4 = (ngroups + 3) / 4;
    k_final<<<blocks4, BLOCK, 0, stream>>>(nf, selfw, bias, deg, out, N);
}

// Round 3
// 998.421 us; speedup vs baseline: 1.0522x; 1.0024x over previous
//
#include <hip/hip_runtime.h>

#define N_F     64
#define N_REL   32
#define BLOCK   256
#define RPB     128          // receivers per k_main block (pow2)
#define SCAN_TILE 2048

// ---------------------------------------------------------------------------
// K1: relation weights W[r][i][o] = sum_b coeff[r][b] * basis[b][i][o]
// ---------------------------------------------------------------------------
__global__ void k_relw(const float* __restrict__ basis,
                       const float* __restrict__ coeff,
                       float* __restrict__ W) {
    int idx = blockIdx.x * blockDim.x + threadIdx.x;
    if (idx >= N_REL * N_F * N_F) return;
    int r  = idx >> 12;
    int io = idx & 4095;
    float acc = 0.f;
#pragma unroll
    for (int b = 0; b < 30; ++b)
        acc += coeff[r * 30 + b] * basis[b * (N_F * N_F) + io];
    W[idx] = acc;
}

// ---------------------------------------------------------------------------
// Counting sort by coarse key = (recv>>7)*32 + rel   (25K bins)
// ---------------------------------------------------------------------------
__global__ void k_hist(const int* __restrict__ rcv, const int* __restrict__ rel,
                       int* __restrict__ cur, int E) {
    int e = blockIdx.x * blockDim.x + threadIdx.x;
    if (e < E) atomicAdd(&cur[(rcv[e] >> 7) * N_REL + rel[e]], 1);
}

__global__ void k_scan_sums(const int* __restrict__ cur, int* __restrict__ part,
                            int nbins) {
    __shared__ int red[BLOCK];
    int base = blockIdx.x * SCAN_TILE;
    int s = 0;
    for (int i = threadIdx.x; i < SCAN_TILE; i += BLOCK) {
        int idx = base + i;
        s += (idx < nbins) ? cur[idx] : 0;
    }
    red[threadIdx.x] = s;
    __syncthreads();
    for (int off = BLOCK / 2; off > 0; off >>= 1) {
        if (threadIdx.x < off) red[threadIdx.x] += red[threadIdx.x + off];
        __syncthreads();
    }
    if (threadIdx.x == 0) part[blockIdx.x] = red[0];
}

__global__ void k_scan_part(int* __restrict__ part, int npart) {
    __shared__ int buf[BLOCK];
    __shared__ int carry;
    if (threadIdx.x == 0) carry = 0;
    __syncthreads();
    int nchunk = (npart + BLOCK - 1) / BLOCK;
    for (int c = 0; c < nchunk; ++c) {
        int i = c * BLOCK + threadIdx.x;
        int v = (i < npart) ? part[i] : 0;
        buf[threadIdx.x] = v;
        __syncthreads();
        for (int off = 1; off < BLOCK; off <<= 1) {
            int t = (threadIdx.x >= off) ? buf[threadIdx.x - off] : 0;
            __syncthreads();
            buf[threadIdx.x] += t;
            __syncthreads();
        }
        int incl = buf[threadIdx.x];
        int excl = incl - v + carry;
        if (i < npart) part[i] = excl;
        int chunk_sum = buf[BLOCK - 1];
        __syncthreads();
        if (threadIdx.x == 0) carry += chunk_sum;
        __syncthreads();
    }
}

__global__ void k_scan_apply(int* __restrict__ cur, const int* __restrict__ part,
                             int nbins) {
    __shared__ int buf[BLOCK];
    int base_t = blockIdx.x * SCAN_TILE + threadIdx.x * 8;
    int loc[8];
    int s = 0;
#pragma unroll
    for (int j = 0; j < 8; ++j) {
        int idx = base_t + j;
        int v = (idx < nbins) ? cur[idx] : 0;
        loc[j] = s;
        s += v;
    }
    buf[threadIdx.x] = s;
    __syncthreads();
    for (int off = 1; off < BLOCK; off <<= 1) {
        int t = (threadIdx.x >= off) ? buf[threadIdx.x - off] : 0;
        __syncthreads();
        buf[threadIdx.x] += t;
        __syncthreads();
    }
    int excl = buf[threadIdx.x] - s + part[blockIdx.x];
#pragma unroll
    for (int j = 0; j < 8; ++j) {
        int idx = base_t + j;
        if (idx < nbins) cur[idx] = loc[j] + excl;
    }
}

// after this, cur[b] == end pointer of bin b
__global__ void k_scatter(const int* __restrict__ snd, const int* __restrict__ rcv,
                          const int* __restrict__ rel, int* __restrict__ cur,
                          int* __restrict__ epack, int E) {
    int e = blockIdx.x * blockDim.x + threadIdx.x;
    if (e < E) {
        int d = rcv[e];
        int pos = atomicAdd(&cur[(d >> 7) * N_REL + rel[e]], 1);
        epack[pos] = snd[e] | ((d & (RPB - 1)) << 17);
    }
}

// ---------------------------------------------------------------------------
// K-main: block owns 128 receivers (sy in LDS). Each wave independently
// handles relations wave, wave+4, ..., keeping W_r column `lane` in 64 VGPRs.
// Per edge: 16 broadcast float4 loads of x, 64 unrolled FMAs, one ds_add_f32.
// No barriers in the edge loop. Epilogue fuses deg-divide + self-loop + bias.
// ---------------------------------------------------------------------------
__global__ void __launch_bounds__(BLOCK) k_main(const float* __restrict__ nf,
                                                const int*   __restrict__ epack,
                                                const int*   __restrict__ cur,
                                                const float* __restrict__ W,
                                                const float* __restrict__ selfw,
                                                const float* __restrict__ bias,
                                                float*       __restrict__ out,
                                                int N) {
    __shared__ float sy[RPB * N_F];   // 32 KB
    __shared__ int   scnt[RPB];       // per-receiver in-degree

    const int tid  = threadIdx.x;
    const int lane = tid & 63;
    const int wave = tid >> 6;
    const int nb0  = blockIdx.x * RPB;
    const int len  = min(RPB, N - nb0);

    {
        float4* sy4 = (float4*)sy;
        for (int i = tid; i < RPB * N_F / 4; i += BLOCK)
            sy4[i] = float4{0.f, 0.f, 0.f, 0.f};
        if (tid < RPB) scnt[tid] = 0;
    }
    __syncthreads();

    for (int r = wave; r < N_REL; r += 4) {
        // W_r column `lane` into registers (64 coalesced wave loads, L2-hot)
        float wc[N_F];
#pragma unroll
        for (int i = 0; i < N_F; ++i)
            wc[i] = W[r * (N_F * N_F) + i * N_F + lane];

        const int b     = blockIdx.x * N_REL + r;
        const int start = (b == 0) ? 0 : cur[b - 1];
        const int end   = cur[b];

        for (int e = start; e < end; ++e) {
            int ep = epack[e];
            int s  = ep & 0x1FFFF;
            int rl = (ep >> 17) & (RPB - 1);
            const float4* xr = (const float4*)(nf + (size_t)s * N_F);

            float a0 = 0.f, a1 = 0.f, a2 = 0.f, a3 = 0.f;
#pragma unroll
            for (int j = 0; j < 16; ++j) {
                float4 xv = xr[j];           // same addr across wave: 1 request
                a0 += xv.x * wc[4 * j + 0];
                a1 += xv.y * wc[4 * j + 1];
                a2 += xv.z * wc[4 * j + 2];
                a3 += xv.w * wc[4 * j + 3];
            }
            unsafeAtomicAdd(&sy[rl * N_F + lane], (a0 + a1) + (a2 + a3));
            if (lane == 0) atomicAdd(&scnt[rl], 1);
        }
    }
    __syncthreads();

    // epilogue: out[n] = sy[n]/max(deg,1) + x[n]@selfW + bias
    float swc[N_F];
#pragma unroll
    for (int i = 0; i < N_F; ++i)
        swc[i] = selfw[i * N_F + lane];
    float bv = bias[lane];

    for (int n = wave; n < len; n += 4) {
        const float4* xr = (const float4*)(nf + (size_t)(nb0 + n) * N_F);
        float a0 = 0.f, a1 = 0.f, a2 = 0.f, a3 = 0.f;
#pragma unroll
        for (int j = 0; j < 16; ++j) {
            float4 xv = xr[j];
            a0 += xv.x * swc[4 * j + 0];
            a1 += xv.y * swc[4 * j + 1];
            a2 += xv.z * swc[4 * j + 2];
            a3 += xv.w * swc[4 * j + 3];
        }
        float dg  = (float)scnt[n];
        float inv = 1.f / (dg < 1.f ? 1.f : dg);
        out[(size_t)(nb0 + n) * N_F + lane] =
            sy[n * N_F + lane] * inv + (a0 + a1) + (a2 + a3) + bv;
    }
}

// ---------------------------------------------------------------------------
extern "C" void kernel_launch(void* const* d_in, const int* in_sizes, int n_in,
                              void* d_out, int out_size, void* d_ws, size_t ws_size,
                              hipStream_t stream) {
    const float* nf    = (const float*)d_in[0];
    const int*   snd   = (const int*)  d_in[1];
    const int*   rcv   = (const int*)  d_in[2];
    const int*   rel   = (const int*)  d_in[3];
    const float* basis = (const float*)d_in[4];
    const float* coeff = (const float*)d_in[5];
    const float* selfw = (const float*)d_in[6];
    const float* bias  = (const float*)d_in[7];
    float*       out   = (float*)d_out;

    const int N = in_sizes[0] / N_F;                  // 100000
    const int E = in_sizes[1];                        // 1000000
    const int NBLK  = (N + RPB - 1) / RPB;            // 782
    const int NBINS = NBLK * N_REL;                   // 25024
    const int NPART = (NBINS + SCAN_TILE - 1) / SCAN_TILE;

    // ws: W (512KB) | cur | part | epack (4MB)
    float* W     = (float*)d_ws;
    int*   cur   = (int*)(W + N_REL * N_F * N_F);
    int*   part  = cur + NBINS;
    int*   epack = part + NPART;

    hipMemsetAsync(cur, 0, (size_t)NBINS * sizeof(int), stream);

    k_relw<<<(N_REL * N_F * N_F + BLOCK - 1) / BLOCK, BLOCK, 0, stream>>>(basis, coeff, W);
    k_hist<<<(E + BLOCK - 1) / BLOCK, BLOCK, 0, stream>>>(rcv, rel, cur, E);
    k_scan_sums <<<NPART, BLOCK, 0, stream>>>(cur, part, NBINS);
    k_scan_part <<<1,     BLOCK, 0, stream>>>(part, NPART);
    k_scan_apply<<<NPART, BLOCK, 0, stream>>>(cur, part, NBINS);
    k_scatter<<<(E + BLOCK - 1) / BLOCK, BLOCK, 0, stream>>>(snd, rcv, rel, cur, epack, E);

    k_main<<<NBLK, BLOCK, 0, stream>>>(nf, epack, cur, W, selfw, bias, out, N);
}

// Round 4
// 737.366 us; speedup vs baseline: 1.4247x; 1.3540x over previous
//
#include <hip/hip_runtime.h>

#define N_F     64
#define N_REL   32
#define BLOCK   256
#define RPB     128          // receivers per k_main block (pow2)
#define SYLD    65           // sy leading dim (stride-65 kills bank conflicts)
#define SCAN_TILE 2048

// ---------------------------------------------------------------------------
// K1: relation weights W[r][i][o] = sum_b coeff[r][b] * basis[b][i][o]
// ---------------------------------------------------------------------------
__global__ void k_relw(const float* __restrict__ basis,
                       const float* __restrict__ coeff,
                       float* __restrict__ W) {
    int idx = blockIdx.x * blockDim.x + threadIdx.x;
    if (idx >= N_REL * N_F * N_F) return;
    int r  = idx >> 12;
    int io = idx & 4095;
    float acc = 0.f;
#pragma unroll
    for (int b = 0; b < 30; ++b)
        acc += coeff[r * 30 + b] * basis[b * (N_F * N_F) + io];
    W[idx] = acc;
}

// ---------------------------------------------------------------------------
// Counting sort by key = (recv>>7)*32 + rel   (25K bins)
// ---------------------------------------------------------------------------
__global__ void k_hist(const int* __restrict__ rcv, const int* __restrict__ rel,
                       int* __restrict__ cur, int E) {
    int e = blockIdx.x * blockDim.x + threadIdx.x;
    if (e < E) atomicAdd(&cur[(rcv[e] >> 7) * N_REL + rel[e]], 1);
}

__global__ void k_scan_sums(const int* __restrict__ cur, int* __restrict__ part,
                            int nbins) {
    __shared__ int red[BLOCK];
    int base = blockIdx.x * SCAN_TILE;
    int s = 0;
    for (int i = threadIdx.x; i < SCAN_TILE; i += BLOCK) {
        int idx = base + i;
        s += (idx < nbins) ? cur[idx] : 0;
    }
    red[threadIdx.x] = s;
    __syncthreads();
    for (int off = BLOCK / 2; off > 0; off >>= 1) {
        if (threadIdx.x < off) red[threadIdx.x] += red[threadIdx.x + off];
        __syncthreads();
    }
    if (threadIdx.x == 0) part[blockIdx.x] = red[0];
}

__global__ void k_scan_part(int* __restrict__ part, int npart) {
    __shared__ int buf[BLOCK];
    __shared__ int carry;
    if (threadIdx.x == 0) carry = 0;
    __syncthreads();
    int nchunk = (npart + BLOCK - 1) / BLOCK;
    for (int c = 0; c < nchunk; ++c) {
        int i = c * BLOCK + threadIdx.x;
        int v = (i < npart) ? part[i] : 0;
        buf[threadIdx.x] = v;
        __syncthreads();
        for (int off = 1; off < BLOCK; off <<= 1) {
            int t = (threadIdx.x >= off) ? buf[threadIdx.x - off] : 0;
            __syncthreads();
            buf[threadIdx.x] += t;
            __syncthreads();
        }
        int incl = buf[threadIdx.x];
        int excl = incl - v + carry;
        if (i < npart) part[i] = excl;
        int chunk_sum = buf[BLOCK - 1];
        __syncthreads();
        if (threadIdx.x == 0) carry += chunk_sum;
        __syncthreads();
    }
}

__global__ void k_scan_apply(int* __restrict__ cur, const int* __restrict__ part,
                             int nbins) {
    __shared__ int buf[BLOCK];
    int base_t = blockIdx.x * SCAN_TILE + threadIdx.x * 8;
    int loc[8];
    int s = 0;
#pragma unroll
    for (int j = 0; j < 8; ++j) {
        int idx = base_t + j;
        int v = (idx < nbins) ? cur[idx] : 0;
        loc[j] = s;
        s += v;
    }
    buf[threadIdx.x] = s;
    __syncthreads();
    for (int off = 1; off < BLOCK; off <<= 1) {
        int t = (threadIdx.x >= off) ? buf[threadIdx.x - off] : 0;
        __syncthreads();
        buf[threadIdx.x] += t;
        __syncthreads();
    }
    int excl = buf[threadIdx.x] - s + part[blockIdx.x];
#pragma unroll
    for (int j = 0; j < 8; ++j) {
        int idx = base_t + j;
        if (idx < nbins) cur[idx] = loc[j] + excl;
    }
}

// after this, cur[b] == end pointer of bin b
__global__ void k_scatter(const int* __restrict__ snd, const int* __restrict__ rcv,
                          const int* __restrict__ rel, int* __restrict__ cur,
                          int* __restrict__ epack, int E) {
    int e = blockIdx.x * blockDim.x + threadIdx.x;
    if (e < E) {
        int d = rcv[e];
        int pos = atomicAdd(&cur[(d >> 7) * N_REL + rel[e]], 1);
        epack[pos] = snd[e] | ((d & (RPB - 1)) << 17);
    }
}

// ---------------------------------------------------------------------------
// K-main, lane-per-edge. Block owns 128 receivers (sy in LDS, stride 65).
// Wave w handles relation bins r = w, w+4, ... Each 64-edge batch: per-lane
// gather of x row (16 dwordx4, all in flight), 4096 FMA wave-instrs with W_r
// as wave-uniform scalar operands, then 64 ds_add_f32 into sy (rl+o banks).
// Epilogue fuses deg-divide + self-loop + bias.
// ---------------------------------------------------------------------------
__global__ void __launch_bounds__(BLOCK) k_main(const float* __restrict__ nf,
                                                const int*   __restrict__ epack,
                                                const int*   __restrict__ cur,
                                                const float* __restrict__ W,
                                                const float* __restrict__ selfw,
                                                const float* __restrict__ bias,
                                                float*       __restrict__ out,
                                                int N) {
    __shared__ float sy[RPB * SYLD];   // 33.3 KB
    __shared__ int   scnt[RPB];

    const int tid  = threadIdx.x;
    const int lane = tid & 63;
    const int wave = tid >> 6;
    const int nb0  = blockIdx.x * RPB;
    const int len  = min(RPB, N - nb0);

    for (int i = tid; i < RPB * SYLD; i += BLOCK) sy[i] = 0.f;
    if (tid < RPB) scnt[tid] = 0;
    __syncthreads();

    for (int r = wave; r < N_REL; r += 4) {
        const int r_u = __builtin_amdgcn_readfirstlane(r);
        const float* __restrict__ Wr = W + (size_t)r_u * (N_F * N_F);

        const int b = blockIdx.x * N_REL + r_u;
        int start = (b == 0) ? 0 : cur[b - 1];
        int end   = cur[b];
        start = __builtin_amdgcn_readfirstlane(start);
        end   = __builtin_amdgcn_readfirstlane(end);

        for (int e0 = start; e0 < end; e0 += 64) {
            const int  e     = e0 + lane;
            const bool valid = e < end;
            const int  ep    = epack[valid ? e : end - 1];
            const int  s     = ep & 0x1FFFF;
            const int  rl    = (ep >> 17) & (RPB - 1);
            const float4* xr = (const float4*)(nf + (size_t)s * N_F);

            float acc[N_F];
#pragma unroll
            for (int o = 0; o < N_F; ++o) acc[o] = 0.f;

            for (int it = 0; it < 4; ++it) {       // rolled: 16 K-slices each
                float4 q0 = xr[4 * it + 0];
                float4 q1 = xr[4 * it + 1];
                float4 q2 = xr[4 * it + 2];
                float4 q3 = xr[4 * it + 3];
                float xv[16] = {q0.x, q0.y, q0.z, q0.w,
                                q1.x, q1.y, q1.z, q1.w,
                                q2.x, q2.y, q2.z, q2.w,
                                q3.x, q3.y, q3.z, q3.w};
#pragma unroll
                for (int i2 = 0; i2 < 16; ++i2) {
                    const float xi = xv[i2];
                    const float* wrow = Wr + (it * 16 + i2) * N_F;
#pragma unroll
                    for (int o = 0; o < N_F; ++o)
                        acc[o] = __builtin_fmaf(xi, wrow[o], acc[o]);
                }
            }

            if (valid) {
                float* yp = &sy[rl * SYLD];
#pragma unroll
                for (int o = 0; o < N_F; ++o)
                    unsafeAtomicAdd(yp + o, acc[o]);
                atomicAdd(&scnt[rl], 1);
            }
        }
    }
    __syncthreads();

    // epilogue: threads 0..len-1, one node each.
    if (tid < len) {
        const int n = tid;
        const float4* xr = (const float4*)(nf + (size_t)(nb0 + n) * N_F);
        float acc[N_F];
#pragma unroll
        for (int o = 0; o < N_F; ++o) acc[o] = 0.f;

        for (int it = 0; it < 4; ++it) {
            float4 q0 = xr[4 * it + 0];
            float4 q1 = xr[4 * it + 1];
            float4 q2 = xr[4 * it + 2];
            float4 q3 = xr[4 * it + 3];
            float xv[16] = {q0.x, q0.y, q0.z, q0.w,
                            q1.x, q1.y, q1.z, q1.w,
                            q2.x, q2.y, q2.z, q2.w,
                            q3.x, q3.y, q3.z, q3.w};
#pragma unroll
            for (int i2 = 0; i2 < 16; ++i2) {
                const float xi = xv[i2];
                const float* wrow = selfw + (it * 16 + i2) * N_F;
#pragma unroll
                for (int o = 0; o < N_F; ++o)
                    acc[o] = __builtin_fmaf(xi, wrow[o], acc[o]);
            }
        }

        float dg  = (float)scnt[n];
        float inv = 1.f / (dg < 1.f ? 1.f : dg);
        float* op = out + (size_t)(nb0 + n) * N_F;
        const float* yp = &sy[n * SYLD];
#pragma unroll
        for (int o = 0; o < N_F; o += 4) {
            float4 v;
            v.x = yp[o + 0] * inv + acc[o + 0] + bias[o + 0];
            v.y = yp[o + 1] * inv + acc[o + 1] + bias[o + 1];
            v.z = yp[o + 2] * inv + acc[o + 2] + bias[o + 2];
            v.w = yp[o + 3] * inv + acc[o + 3] + bias[o + 3];
            *(float4*)(op + o) = v;
        }
    }
}

// ---------------------------------------------------------------------------
extern "C" void kernel_launch(void* const* d_in, const int* in_sizes, int n_in,
                              void* d_out, int out_size, void* d_ws, size_t ws_size,
                              hipStream_t stream) {
    const float* nf    = (const float*)d_in[0];
    const int*   snd   = (const int*)  d_in[1];
    const int*   rcv   = (const int*)  d_in[2];
    const int*   rel   = (const int*)  d_in[3];
    const float* basis = (const float*)d_in[4];
    const float* coeff = (const float*)d_in[5];
    const float* selfw = (const float*)d_in[6];
    const float* bias  = (const float*)d_in[7];
    float*       out   = (float*)d_out;

    const int N = in_sizes[0] / N_F;                  // 100000
    const int E = in_sizes[1];                        // 1000000
    const int NBLK  = (N + RPB - 1) / RPB;            // 782
    const int NBINS = NBLK * N_REL;                   // 25024
    const int NPART = (NBINS + SCAN_TILE - 1) / SCAN_TILE;

    float* W     = (float*)d_ws;
    int*   cur   = (int*)(W + N_REL * N_F * N_F);
    int*   part  = cur + NBINS;
    int*   epack = part + NPART;

    hipMemsetAsync(cur, 0, (size_t)NBINS * sizeof(int), stream);

    k_relw<<<(N_REL * N_F * N_F + BLOCK - 1) / BLOCK, BLOCK, 0, stream>>>(basis, coeff, W);
    k_hist<<<(E + BLOCK - 1) / BLOCK, BLOCK, 0, stream>>>(rcv, rel, cur, E);
    k_scan_sums <<<NPART, BLOCK, 0, stream>>>(cur, part, NBINS);
    k_scan_part <<<1,     BLOCK, 0, stream>>>(part, NPART);
    k_scan_apply<<<NPART, BLOCK, 0, stream>>>(cur, part, NBINS);
    k_scatter<<<(E + BLOCK - 1) / BLOCK, BLOCK, 0, stream>>>(snd, rcv, rel, cur, epack, E);

    k_main<<<NBLK, BLOCK, 0, stream>>>(nf, epack, cur, W, selfw, bias, out, N);
}

// Round 5
// 656.415 us; speedup vs baseline: 1.6004x; 1.1233x over previous
//
#include <hip/hip_runtime.h>

#define N_F     64
#define N_REL   32
#define BLOCK   256
#define RPB     128          // receivers per k_main block (pow2)
#define SYLD    65           // sy leading dim (stride-65: bank = (rl+feat)&31)
#define SCAN_TILE 2048

typedef __attribute__((ext_vector_type(8))) short bf16x8;   // 8 bf16 = 4 VGPRs
typedef __attribute__((ext_vector_type(4))) float f32x4;

__device__ __forceinline__ unsigned short f2bf(float f) {
    unsigned u = __float_as_uint(f);
    u += 0x7FFF + ((u >> 16) & 1);          // RNE
    return (unsigned short)(u >> 16);
}

// ---------------------------------------------------------------------------
// K0: cast node features fp32 -> bf16 (read once, 12.8 MB out)
// ---------------------------------------------------------------------------
__global__ void k_cast(const float* __restrict__ nf, unsigned short* __restrict__ xbf,
                       int total4) {
    int i = blockIdx.x * blockDim.x + threadIdx.x;
    if (i >= total4) return;
    float4 v = ((const float4*)nf)[i];
    ushort4 o;
    o.x = f2bf(v.x); o.y = f2bf(v.y); o.z = f2bf(v.z); o.w = f2bf(v.w);
    ((ushort4*)xbf)[i] = o;
}

// ---------------------------------------------------------------------------
// K1: relation weights -> bf16, pre-shuffled into MFMA B-fragment layout.
// B-frag for (r, ks, nt): element j of lane l = W[r][ks*32 + (l>>4)*8 + j][nt*16 + (l&15)]
// stored at Wsh[((((r*2+ks)*4+nt)*64 + l)*8 + j)]
// ---------------------------------------------------------------------------
__global__ void k_relw(const float* __restrict__ basis,
                       const float* __restrict__ coeff,
                       unsigned short* __restrict__ Wsh) {
    int idx = blockIdx.x * blockDim.x + threadIdx.x;
    if (idx >= N_REL * N_F * N_F) return;
    int r  = idx >> 12;
    int io = idx & 4095;          // k*64 + n
    int k  = io >> 6;
    int n  = io & 63;
    float acc = 0.f;
#pragma unroll
    for (int b = 0; b < 30; ++b)
        acc += coeff[r * 30 + b] * basis[b * (N_F * N_F) + io];
    int ks = k >> 5, kk = k & 31;
    int nt = n >> 4, nl = n & 15;
    int lane = ((kk >> 3) << 4) | nl;
    int j    = kk & 7;
    Wsh[((((r * 2 + ks) * 4 + nt) * 64 + lane) << 3) + j] = f2bf(acc);
}

// ---------------------------------------------------------------------------
// Counting sort by key = (recv>>7)*32 + rel   (25K bins)
// ---------------------------------------------------------------------------
__global__ void k_hist(const int* __restrict__ rcv, const int* __restrict__ rel,
                       int* __restrict__ cur, int E) {
    int e = blockIdx.x * blockDim.x + threadIdx.x;
    if (e < E) atomicAdd(&cur[(rcv[e] >> 7) * N_REL + rel[e]], 1);
}

__global__ void k_scan_sums(const int* __restrict__ cur, int* __restrict__ part,
                            int nbins) {
    __shared__ int red[BLOCK];
    int base = blockIdx.x * SCAN_TILE;
    int s = 0;
    for (int i = threadIdx.x; i < SCAN_TILE; i += BLOCK) {
        int idx = base + i;
        s += (idx < nbins) ? cur[idx] : 0;
    }
    red[threadIdx.x] = s;
    __syncthreads();
    for (int off = BLOCK / 2; off > 0; off >>= 1) {
        if (threadIdx.x < off) red[threadIdx.x] += red[threadIdx.x + off];
        __syncthreads();
    }
    if (threadIdx.x == 0) part[blockIdx.x] = red[0];
}

__global__ void k_scan_part(int* __restrict__ part, int npart) {
    __shared__ int buf[BLOCK];
    __shared__ int carry;
    if (threadIdx.x == 0) carry = 0;
    __syncthreads();
    int nchunk = (npart + BLOCK - 1) / BLOCK;
    for (int c = 0; c < nchunk; ++c) {
        int i = c * BLOCK + threadIdx.x;
        int v = (i < npart) ? part[i] : 0;
        buf[threadIdx.x] = v;
        __syncthreads();
        for (int off = 1; off < BLOCK; off <<= 1) {
            int t = (threadIdx.x >= off) ? buf[threadIdx.x - off] : 0;
            __syncthreads();
            buf[threadIdx.x] += t;
            __syncthreads();
        }
        int incl = buf[threadIdx.x];
        int excl = incl - v + carry;
        if (i < npart) part[i] = excl;
        int chunk_sum = buf[BLOCK - 1];
        __syncthreads();
        if (threadIdx.x == 0) carry += chunk_sum;
        __syncthreads();
    }
}

__global__ void k_scan_apply(int* __restrict__ cur, const int* __restrict__ part,
                             int nbins) {
    __shared__ int buf[BLOCK];
    int base_t = blockIdx.x * SCAN_TILE + threadIdx.x * 8;
    int loc[8];
    int s = 0;
#pragma unroll
    for (int j = 0; j < 8; ++j) {
        int idx = base_t + j;
        int v = (idx < nbins) ? cur[idx] : 0;
        loc[j] = s;
        s += v;
    }
    buf[threadIdx.x] = s;
    __syncthreads();
    for (int off = 1; off < BLOCK; off <<= 1) {
        int t = (threadIdx.x >= off) ? buf[threadIdx.x - off] : 0;
        __syncthreads();
        buf[threadIdx.x] += t;
        __syncthreads();
    }
    int excl = buf[threadIdx.x] - s + part[blockIdx.x];
#pragma unroll
    for (int j = 0; j < 8; ++j) {
        int idx = base_t + j;
        if (idx < nbins) cur[idx] = loc[j] + excl;
    }
}

// after this, cur[b] == end pointer of bin b
__global__ void k_scatter(const int* __restrict__ snd, const int* __restrict__ rcv,
                          const int* __restrict__ rel, int* __restrict__ cur,
                          int* __restrict__ epack, int E) {
    int e = blockIdx.x * blockDim.x + threadIdx.x;
    if (e < E) {
        int d = rcv[e];
        int pos = atomicAdd(&cur[(d >> 7) * N_REL + rel[e]], 1);
        epack[pos] = snd[e] | ((d & (RPB - 1)) << 17);
    }
}

// ---------------------------------------------------------------------------
// K-main, MFMA. Block owns 128 receivers (sy in LDS). Wave w handles bins
// r = w, w+4, ...: W_r held as 8 B-frags in VGPRs; per 16-edge tile: A-frags
// gathered straight from bf16 nf (1 dwordx4/lane/kslice), 8 MFMAs, C
// scattered to sy via predicated ds_add_f32 (rl via __shfl). Epilogue fuses
// deg-divide + fp32 self-loop + bias.
// ---------------------------------------------------------------------------
__global__ void __launch_bounds__(BLOCK) k_main(const unsigned short* __restrict__ xbf,
                                                const float* __restrict__ nf,
                                                const int*   __restrict__ epack,
                                                const int*   __restrict__ cur,
                                                const unsigned short* __restrict__ Wsh,
                                                const float* __restrict__ selfw,
                                                const float* __restrict__ bias,
                                                float*       __restrict__ out,
                                                int N) {
    __shared__ float sy[RPB * SYLD];   // 33.3 KB
    __shared__ int   scnt[RPB];

    const int tid  = threadIdx.x;
    const int lane = tid & 63;
    const int wave = tid >> 6;
    const int nb0  = blockIdx.x * RPB;
    const int len  = min(RPB, N - nb0);

    for (int i = tid; i < RPB * SYLD; i += BLOCK) sy[i] = 0.f;
    if (tid < RPB) scnt[tid] = 0;
    __syncthreads();

    const int row = lane & 15;     // edge row within tile
    const int kg  = lane >> 4;     // k-group

    for (int r = wave; r < N_REL; r += 4) {
        // W_r: 8 B-frags (2 kslices x 4 ntiles), coalesced dwordx4 each
        bf16x8 wf[2][4];
#pragma unroll
        for (int ks = 0; ks < 2; ++ks)
#pragma unroll
            for (int nt = 0; nt < 4; ++nt)
                wf[ks][nt] = *(const bf16x8*)(Wsh + ((((r * 2 + ks) * 4 + nt) * 64 + lane) << 3));

        const int b     = blockIdx.x * N_REL + r;
        const int start = (b == 0) ? 0 : cur[b - 1];
        const int end   = cur[b];

        for (int tb = start; tb < end; tb += 16) {
            const int  e     = tb + row;
            const bool valid = e < end;
            const int  ep    = epack[valid ? e : end - 1];
            const int  s     = ep & 0x1FFFF;
            const int  rl    = valid ? ((ep >> 17) & (RPB - 1)) : -1;

            const size_t xb = ((size_t)s << 6) + (kg << 3);
            bf16x8 a0 = *(const bf16x8*)(xbf + xb);        // k-slice 0
            bf16x8 a1 = *(const bf16x8*)(xbf + xb + 32);   // k-slice 1

            f32x4 acc[4];
#pragma unroll
            for (int nt = 0; nt < 4; ++nt) {
                acc[nt] = (f32x4){0.f, 0.f, 0.f, 0.f};
                acc[nt] = __builtin_amdgcn_mfma_f32_16x16x32_bf16(a0, wf[0][nt], acc[nt], 0, 0, 0);
                acc[nt] = __builtin_amdgcn_mfma_f32_16x16x32_bf16(a1, wf[1][nt], acc[nt], 0, 0, 0);
            }

            if (lane < 16 && valid) atomicAdd(&scnt[rl], 1);

            int rlr[4];
#pragma unroll
            for (int reg = 0; reg < 4; ++reg)
                rlr[reg] = __shfl(rl, (kg << 2) + reg);    // rl of edge row kg*4+reg

#pragma unroll
            for (int nt = 0; nt < 4; ++nt) {
#pragma unroll
                for (int reg = 0; reg < 4; ++reg) {
                    if (rlr[reg] >= 0)
                        unsafeAtomicAdd(&sy[rlr[reg] * SYLD + nt * 16 + row], acc[nt][reg]);
                }
            }
        }
    }
    __syncthreads();

    // epilogue: out[n] = sy[n]/max(deg,1) + x[n]@selfW + bias   (fp32 exact)
    if (tid < len) {
        const int n = tid;
        const float4* xr = (const float4*)(nf + (size_t)(nb0 + n) * N_F);
        float acc[N_F];
#pragma unroll
        for (int o = 0; o < N_F; ++o) acc[o] = 0.f;

        for (int it = 0; it < 4; ++it) {
            float4 q0 = xr[4 * it + 0];
            float4 q1 = xr[4 * it + 1];
            float4 q2 = xr[4 * it + 2];
            float4 q3 = xr[4 * it + 3];
            float xv[16] = {q0.x, q0.y, q0.z, q0.w,
                            q1.x, q1.y, q1.z, q1.w,
                            q2.x, q2.y, q2.z, q2.w,
                            q3.x, q3.y, q3.z, q3.w};
#pragma unroll
            for (int i2 = 0; i2 < 16; ++i2) {
                const float xi = xv[i2];
                const float* wrow = selfw + (it * 16 + i2) * N_F;
#pragma unroll
                for (int o = 0; o < N_F; ++o)
                    acc[o] = __builtin_fmaf(xi, wrow[o], acc[o]);
            }
        }

        float dg  = (float)scnt[n];
        float inv = 1.f / (dg < 1.f ? 1.f : dg);
        float* op = out + (size_t)(nb0 + n) * N_F;
        const float* yp = &sy[n * SYLD];
#pragma unroll
        for (int o = 0; o < N_F; o += 4) {
            float4 v;
            v.x = yp[o + 0] * inv + acc[o + 0] + bias[o + 0];
            v.y = yp[o + 1] * inv + acc[o + 1] + bias[o + 1];
            v.z = yp[o + 2] * inv + acc[o + 2] + bias[o + 2];
            v.w = yp[o + 3] * inv + acc[o + 3] + bias[o + 3];
            *(float4*)(op + o) = v;
        }
    }
}

// ---------------------------------------------------------------------------
extern "C" void kernel_launch(void* const* d_in, const int* in_sizes, int n_in,
                              void* d_out, int out_size, void* d_ws, size_t ws_size,
                              hipStream_t stream) {
    const float* nf    = (const float*)d_in[0];
    const int*   snd   = (const int*)  d_in[1];
    const int*   rcv   = (const int*)  d_in[2];
    const int*   rel   = (const int*)  d_in[3];
    const float* basis = (const float*)d_in[4];
    const float* coeff = (const float*)d_in[5];
    const float* selfw = (const float*)d_in[6];
    const float* bias  = (const float*)d_in[7];
    float*       out   = (float*)d_out;

    const int N = in_sizes[0] / N_F;                  // 100000
    const int E = in_sizes[1];                        // 1000000
    const int NBLK  = (N + RPB - 1) / RPB;            // 782
    const int NBINS = NBLK * N_REL;                   // 25024
    const int NPART = (NBINS + SCAN_TILE - 1) / SCAN_TILE;

    // ws: Wsh bf16 (256 KB) | xbf bf16 (12.8 MB) | cur | part | epack (4 MB)
    unsigned short* Wsh = (unsigned short*)d_ws;
    unsigned short* xbf = Wsh + (size_t)N_REL * N_F * N_F;
    int* cur   = (int*)(xbf + (size_t)N * N_F);
    int* part  = cur + NBINS;
    int* epack = part + NPART;

    hipMemsetAsync(cur, 0, (size_t)NBINS * sizeof(int), stream);

    k_cast<<<(N * N_F / 4 + BLOCK - 1) / BLOCK, BLOCK, 0, stream>>>(nf, xbf, N * N_F / 4);
    k_relw<<<(N_REL * N_F * N_F + BLOCK - 1) / BLOCK, BLOCK, 0, stream>>>(basis, coeff, Wsh);
    k_hist<<<(E + BLOCK - 1) / BLOCK, BLOCK, 0, stream>>>(rcv, rel, cur, E);
    k_scan_sums <<<NPART, BLOCK, 0, stream>>>(cur, part, NBINS);
    k_scan_part <<<1,     BLOCK, 0, stream>>>(part, NPART);
    k_scan_apply<<<NPART, BLOCK, 0, stream>>>(cur, part, NBINS);
    k_scatter<<<(E + BLOCK - 1) / BLOCK, BLOCK, 0, stream>>>(snd, rcv, rel, cur, epack, E);

    k_main<<<NBLK, BLOCK, 0, stream>>>(xbf, nf, epack, cur, Wsh, selfw, bias, out, N);
}

// Round 6
// 605.292 us; speedup vs baseline: 1.7356x; 1.0845x over previous
//
#include <hip/hip_runtime.h>

#define N_F     64
#define N_REL   32
#define BLOCK   256
#define SCAN_TILE 2048

typedef __attribute__((ext_vector_type(8))) short bf16x8;   // 8 bf16 = 4 VGPRs
typedef __attribute__((ext_vector_type(4))) float f32x4;

__device__ __forceinline__ unsigned short f2bf(float f) {
    unsigned u = __float_as_uint(f);
    u += 0x7FFF + ((u >> 16) & 1);          // RNE
    return (unsigned short)(u >> 16);
}

// ---------------------------------------------------------------------------
// K0: cast node features fp32 -> bf16
// ---------------------------------------------------------------------------
__global__ void k_cast(const float* __restrict__ nf, unsigned short* __restrict__ xbf,
                       int total4) {
    int i = blockIdx.x * blockDim.x + threadIdx.x;
    if (i >= total4) return;
    float4 v = ((const float4*)nf)[i];
    ushort4 o;
    o.x = f2bf(v.x); o.y = f2bf(v.y); o.z = f2bf(v.z); o.w = f2bf(v.w);
    ((ushort4*)xbf)[i] = o;
}

// ---------------------------------------------------------------------------
// K1: relation weights -> bf16 in MFMA B-fragment layout (verified R5).
// ---------------------------------------------------------------------------
__global__ void k_relw(const float* __restrict__ basis,
                       const float* __restrict__ coeff,
                       unsigned short* __restrict__ Wsh) {
    int idx = blockIdx.x * blockDim.x + threadIdx.x;
    if (idx >= N_REL * N_F * N_F) return;
    int r  = idx >> 12;
    int io = idx & 4095;          // k*64 + n
    int k  = io >> 6;
    int n  = io & 63;
    float acc = 0.f;
#pragma unroll
    for (int b = 0; b < 30; ++b)
        acc += coeff[r * 30 + b] * basis[b * (N_F * N_F) + io];
    int ks = k >> 5, kk = k & 31;
    int nt = n >> 4, nl = n & 15;
    int lane = ((kk >> 3) << 4) | nl;
    int j    = kk & 7;
    Wsh[((((r * 2 + ks) * 4 + nt) * 64 + lane) << 3) + j] = f2bf(acc);
}

// ---------------------------------------------------------------------------
// Sort 1: by relation (32 bins), block-aggregated
// ---------------------------------------------------------------------------
__global__ void k_hist1(const int* __restrict__ rel, int* __restrict__ cnt1, int E) {
    __shared__ int h[N_REL];
    if (threadIdx.x < N_REL) h[threadIdx.x] = 0;
    __syncthreads();
    int e = blockIdx.x * blockDim.x + threadIdx.x;
    if (e < E) atomicAdd(&h[rel[e]], 1);
    __syncthreads();
    if (threadIdx.x < N_REL && h[threadIdx.x]) atomicAdd(&cnt1[threadIdx.x], h[threadIdx.x]);
}

// single-thread scan with 16-alignment; cur1 = running cursors
__global__ void k_scan1(const int* __restrict__ cnt1, int* __restrict__ base1,
                        int* __restrict__ cur1, int Ppad) {
    if (threadIdx.x == 0 && blockIdx.x == 0) {
        int acc = 0;
        for (int r = 0; r < N_REL; ++r) {
            base1[r] = acc;
            cur1[r]  = acc;
            acc += (cnt1[r] + 15) & ~15;
        }
        base1[N_REL] = Ppad;
    }
}

__global__ void k_scatter1(const int* __restrict__ snd, const int* __restrict__ rcv,
                           const int* __restrict__ rel, int* __restrict__ cur1,
                           int* __restrict__ esrc, int* __restrict__ erecv, int E) {
    __shared__ int h[N_REL], hb[N_REL];
    if (threadIdx.x < N_REL) h[threadIdx.x] = 0;
    __syncthreads();
    int e = blockIdx.x * blockDim.x + threadIdx.x;
    int r = -1;
    if (e < E) { r = rel[e]; atomicAdd(&h[r], 1); }
    __syncthreads();
    if (threadIdx.x < N_REL && h[threadIdx.x])
        hb[threadIdx.x] = atomicAdd(&cur1[threadIdx.x], h[threadIdx.x]);
    __syncthreads();
    if (threadIdx.x < N_REL) h[threadIdx.x] = 0;
    __syncthreads();
    if (e < E) {
        int rank = atomicAdd(&h[r], 1);
        int pos  = hb[r] + rank;
        esrc[pos]  = snd[e];
        erecv[pos] = rcv[e];
    }
}

// ---------------------------------------------------------------------------
// Sort 2: by receiver (N bins) over the rel-sorted list
// ---------------------------------------------------------------------------
__global__ void k_hist2(const int* __restrict__ rcv, int* __restrict__ cnt2, int E) {
    int e = blockIdx.x * blockDim.x + threadIdx.x;
    if (e < E) atomicAdd(&cnt2[rcv[e]], 1);
}

__global__ void k_scan_sums(const int* __restrict__ cur, int* __restrict__ part,
                            int nbins) {
    __shared__ int red[BLOCK];
    int base = blockIdx.x * SCAN_TILE;
    int s = 0;
    for (int i = threadIdx.x; i < SCAN_TILE; i += BLOCK) {
        int idx = base + i;
        s += (idx < nbins) ? cur[idx] : 0;
    }
    red[threadIdx.x] = s;
    __syncthreads();
    for (int off = BLOCK / 2; off > 0; off >>= 1) {
        if (threadIdx.x < off) red[threadIdx.x] += red[threadIdx.x + off];
        __syncthreads();
    }
    if (threadIdx.x == 0) part[blockIdx.x] = red[0];
}

__global__ void k_scan_part(int* __restrict__ part, int npart) {
    __shared__ int buf[BLOCK];
    __shared__ int carry;
    if (threadIdx.x == 0) carry = 0;
    __syncthreads();
    int nchunk = (npart + BLOCK - 1) / BLOCK;
    for (int c = 0; c < nchunk; ++c) {
        int i = c * BLOCK + threadIdx.x;
        int v = (i < npart) ? part[i] : 0;
        buf[threadIdx.x] = v;
        __syncthreads();
        for (int off = 1; off < BLOCK; off <<= 1) {
            int t = (threadIdx.x >= off) ? buf[threadIdx.x - off] : 0;
            __syncthreads();
            buf[threadIdx.x] += t;
            __syncthreads();
        }
        int incl = buf[threadIdx.x];
        int excl = incl - v + carry;
        if (i < npart) part[i] = excl;
        int chunk_sum = buf[BLOCK - 1];
        __syncthreads();
        if (threadIdx.x == 0) carry += chunk_sum;
        __syncthreads();
    }
}

__global__ void k_scan_apply(int* __restrict__ cur, const int* __restrict__ part,
                             int nbins) {
    __shared__ int buf[BLOCK];
    int base_t = blockIdx.x * SCAN_TILE + threadIdx.x * 8;
    int loc[8];
    int s = 0;
#pragma unroll
    for (int j = 0; j < 8; ++j) {
        int idx = base_t + j;
        int v = (idx < nbins) ? cur[idx] : 0;
        loc[j] = s;
        s += v;
    }
    buf[threadIdx.x] = s;
    __syncthreads();
    for (int off = 1; off < BLOCK; off <<= 1) {
        int t = (threadIdx.x >= off) ? buf[threadIdx.x - off] : 0;
        __syncthreads();
        buf[threadIdx.x] += t;
        __syncthreads();
    }
    int excl = buf[threadIdx.x] - s + part[blockIdx.x];
#pragma unroll
    for (int j = 0; j < 8; ++j) {
        int idx = base_t + j;
        if (idx < nbins) cur[idx] = loc[j] + excl;
    }
}

// after this, cur2[n] == end pointer of receiver n's span; eidx = rel-sorted pos
__global__ void k_scatter2(const int* __restrict__ erecv, int* __restrict__ cur2,
                           int* __restrict__ eidx, int P, int N) {
    int j = blockIdx.x * blockDim.x + threadIdx.x;
    if (j < P) {
        int d = erecv[j];
        if ((unsigned)d < (unsigned)N) {
            int pos = atomicAdd(&cur2[d], 1);
            eidx[pos] = j;
        }
    }
}

// tile -> relation (segments are 16-aligned, so each tile is single-rel)
__global__ void k_tilerel(const int* __restrict__ base1, unsigned char* __restrict__ trel,
                          int T) {
    int t = blockIdx.x * blockDim.x + threadIdx.x;
    if (t >= T) return;
    int p = t << 4;
    int r = 0;
#pragma unroll
    for (int i = 1; i < N_REL; ++i) r += (p >= base1[i]);
    trel[t] = (unsigned char)r;
}

// ---------------------------------------------------------------------------
// Phase A: per-tile GEMM -> row-major bf16 edge outputs. No barriers, no
// atomics. Wave-private LDS transpose (explicit lgkmcnt wait, waves never
// share the buffer).
// ---------------------------------------------------------------------------
__global__ void __launch_bounds__(BLOCK) k_gemm(const unsigned short* __restrict__ xbf,
                                                const int* __restrict__ esrc,
                                                const unsigned char* __restrict__ trel,
                                                const unsigned short* __restrict__ Wsh,
                                                unsigned short* __restrict__ eoutb,
                                                int T, int tpw) {
    __shared__ float ts[4][16 * 68];        // per-wave 16x64 transpose, stride 68
    const int tid  = threadIdx.x;
    const int lane = tid & 63;
    const int wave = tid >> 6;
    float* tb = ts[wave];

    const int gw = blockIdx.x * 4 + wave;
    const int t0 = gw * tpw;
    const int t1 = min(t0 + tpw, T);

    const int row = lane & 15;
    const int kg  = lane >> 4;
    const int rr  = lane >> 2;      // store-phase row
    const int ch  = lane & 3;       // store-phase 16-col chunk

    int curR = -1;
    bf16x8 wf[2][4];

    for (int t = t0; t < t1; ++t) {
        const int r = trel[t];
        if (r != curR) {
            curR = r;
#pragma unroll
            for (int ks = 0; ks < 2; ++ks)
#pragma unroll
                for (int nt = 0; nt < 4; ++nt)
                    wf[ks][nt] = *(const bf16x8*)(Wsh + ((((r * 2 + ks) * 4 + nt) * 64 + lane) << 3));
        }

        const int p = (t << 4) + row;
        const int s = esrc[p];
        const size_t xb = ((size_t)s << 6) + (kg << 3);
        bf16x8 a0 = *(const bf16x8*)(xbf + xb);
        bf16x8 a1 = *(const bf16x8*)(xbf + xb + 32);

        f32x4 acc[4];
#pragma unroll
        for (int nt = 0; nt < 4; ++nt) {
            acc[nt] = (f32x4){0.f, 0.f, 0.f, 0.f};
            acc[nt] = __builtin_amdgcn_mfma_f32_16x16x32_bf16(a0, wf[0][nt], acc[nt], 0, 0, 0);
            acc[nt] = __builtin_amdgcn_mfma_f32_16x16x32_bf16(a1, wf[1][nt], acc[nt], 0, 0, 0);
        }

        // C-layout (col=lane&15, row=kg*4+reg) -> LDS row-major
#pragma unroll
        for (int nt = 0; nt < 4; ++nt)
#pragma unroll
            for (int reg = 0; reg < 4; ++reg)
                tb[(kg * 4 + reg) * 68 + nt * 16 + (lane & 15)] = acc[nt][reg];

        asm volatile("s_waitcnt lgkmcnt(0)" ::: "memory");   // wave-local RAW

        const float* src = tb + rr * 68 + ch * 16;
        unsigned pk[8];
#pragma unroll
        for (int q = 0; q < 4; ++q) {
            float4 v = *(const float4*)(src + q * 4);
            pk[2 * q]     = (unsigned)f2bf(v.x) | ((unsigned)f2bf(v.y) << 16);
            pk[2 * q + 1] = (unsigned)f2bf(v.z) | ((unsigned)f2bf(v.w) << 16);
        }
        unsigned short* dst = eoutb + ((size_t)((t << 4) + rr)) * 64 + ch * 16;
        uint4 v0; v0.x = pk[0]; v0.y = pk[1]; v0.z = pk[2]; v0.w = pk[3];
        uint4 v1; v1.x = pk[4]; v1.y = pk[5]; v1.z = pk[6]; v1.w = pk[7];
        *(uint4*)dst       = v0;
        *(uint4*)(dst + 8) = v1;
    }
}

// ---------------------------------------------------------------------------
// Phase B: wave per receiver, lane = feature. Register accumulate, fused
// deg-divide + fp32 self-loop + bias. No atomics, no LDS.
// ---------------------------------------------------------------------------
__global__ void __launch_bounds__(BLOCK) k_recv(const float* __restrict__ nf,
                                                const unsigned short* __restrict__ eoutb,
                                                const int* __restrict__ eidx,
                                                const int* __restrict__ cur2,
                                                const float* __restrict__ selfw,
                                                const float* __restrict__ bias,
                                                float* __restrict__ out,
                                                int N, int rpw) {
    const int tid  = threadIdx.x;
    const int lane = tid & 63;
    const int wave = tid >> 6;
    const int gw   = blockIdx.x * 4 + wave;
    const int n0   = gw * rpw;
    const int n1   = min(n0 + rpw, N);
    if (n0 >= N) return;

    float swcol[N_F];
#pragma unroll
    for (int i = 0; i < N_F; ++i) swcol[i] = selfw[i * N_F + lane];
    const float bv = bias[lane];

    for (int n = n0; n < n1; ++n) {
        const int st = (n == 0) ? 0 : cur2[n - 1];
        const int en = cur2[n];

        float acc = 0.f;
        for (int j = st; j < en; ++j) {
            int p = eidx[j];                                  // broadcast
            acc += __uint_as_float((unsigned)eoutb[(size_t)p * 64 + lane] << 16);
        }

        const float4* xr = (const float4*)(nf + (size_t)n * N_F);
        float s0 = 0.f, s1 = 0.f, s2 = 0.f, s3 = 0.f;
#pragma unroll
        for (int q = 0; q < 16; ++q) {
            float4 xv = xr[q];                                // broadcast
            s0 = __builtin_fmaf(xv.x, swcol[4 * q + 0], s0);
            s1 = __builtin_fmaf(xv.y, swcol[4 * q + 1], s1);
            s2 = __builtin_fmaf(xv.z, swcol[4 * q + 2], s2);
            s3 = __builtin_fmaf(xv.w, swcol[4 * q + 3], s3);
        }

        float dg  = (float)(en - st);
        float inv = 1.f / (dg < 1.f ? 1.f : dg);
        out[(size_t)n * N_F + lane] = acc * inv + (s0 + s1) + (s2 + s3) + bv;
    }
}

// ---------------------------------------------------------------------------
extern "C" void kernel_launch(void* const* d_in, const int* in_sizes, int n_in,
                              void* d_out, int out_size, void* d_ws, size_t ws_size,
                              hipStream_t stream) {
    const float* nf    = (const float*)d_in[0];
    const int*   snd   = (const int*)  d_in[1];
    const int*   rcv   = (const int*)  d_in[2];
    const int*   rel   = (const int*)  d_in[3];
    const float* basis = (const float*)d_in[4];
    const float* coeff = (const float*)d_in[5];
    const float* selfw = (const float*)d_in[6];
    const float* bias  = (const float*)d_in[7];
    float*       out   = (float*)d_out;

    const int N = in_sizes[0] / N_F;                  // 100000
    const int E = in_sizes[1];                        // 1000000
    const int Ppad = (E + N_REL * 15 + 15) & ~15;     // padded rel-sorted length
    const int T    = Ppad >> 4;                       // total 16-edge tiles
    const int NPART = (N + SCAN_TILE - 1) / SCAN_TILE;

    // ws layout (eoutb first for 16B alignment of uint4 stores)
    unsigned short* eoutb = (unsigned short*)d_ws;                    // Ppad*64 bf16
    unsigned short* Wsh   = eoutb + (size_t)Ppad * N_F;               // 131072
    unsigned short* xbf   = Wsh + (size_t)N_REL * N_F * N_F;          // N*64
    int* base1 = (int*)(xbf + (size_t)N * N_F);                       // 33 (+pad)
    int* cur1  = base1 + 64;
    int* cnt1  = cur1 + 32;
    int* part  = cnt1 + 32;
    int* cnt2  = part + 64;                                           // N  (becomes cur2)
    int* esrc  = cnt2 + N;                                            // Ppad
    int* erecv = esrc + Ppad;                                         // Ppad
    int* eidx  = erecv + Ppad;                                        // E
    unsigned char* trel = (unsigned char*)(eidx + E);                 // T

    hipMemsetAsync(cnt1, 0, 32 * sizeof(int), stream);
    hipMemsetAsync(cnt2, 0, (size_t)N * sizeof(int), stream);
    hipMemsetAsync(esrc, 0, (size_t)Ppad * sizeof(int), stream);      // pads -> node 0
    hipMemsetAsync(erecv, 0xFF, (size_t)Ppad * sizeof(int), stream);  // pads -> invalid

    k_cast<<<(N * N_F / 4 + BLOCK - 1) / BLOCK, BLOCK, 0, stream>>>(nf, xbf, N * N_F / 4);
    k_relw<<<(N_REL * N_F * N_F + BLOCK - 1) / BLOCK, BLOCK, 0, stream>>>(basis, coeff, Wsh);

    k_hist1<<<(E + BLOCK - 1) / BLOCK, BLOCK, 0, stream>>>(rel, cnt1, E);
    k_scan1<<<1, 64, 0, stream>>>(cnt1, base1, cur1, Ppad);
    k_scatter1<<<(E + BLOCK - 1) / BLOCK, BLOCK, 0, stream>>>(snd, rcv, rel, cur1, esrc, erecv, E);

    k_hist2<<<(E + BLOCK - 1) / BLOCK, BLOCK, 0, stream>>>(rcv, cnt2, E);
    k_scan_sums <<<NPART, BLOCK, 0, stream>>>(cnt2, part, N);
    k_scan_part <<<1,     BLOCK, 0, stream>>>(part, NPART);
    k_scan_apply<<<NPART, BLOCK, 0, stream>>>(cnt2, part, N);
    k_scatter2<<<(Ppad + BLOCK - 1) / BLOCK, BLOCK, 0, stream>>>(erecv, cnt2, eidx, Ppad, N);

    k_tilerel<<<(T + BLOCK - 1) / BLOCK, BLOCK, 0, stream>>>(base1, trel, T);

    const int GEMM_BLOCKS = 512;                       // 2048 waves
    const int tpw = (T + GEMM_BLOCKS * 4 - 1) / (GEMM_BLOCKS * 4);
    k_gemm<<<GEMM_BLOCKS, BLOCK, 0, stream>>>(xbf, esrc, trel, Wsh, eoutb, T, tpw);

    const int RECV_BLOCKS = 1024;                      // 4096 waves
    const int rpw = (N + RECV_BLOCKS * 4 - 1) / (RECV_BLOCKS * 4);
    k_recv<<<RECV_BLOCKS, BLOCK, 0, stream>>>(nf, eoutb, eidx, cnt2, selfw, bias, out, N, rpw);
}

// Round 7
// 445.083 us; speedup vs baseline: 2.3603x; 1.3600x over previous
//
#include <hip/hip_runtime.h>

#define N_F     64
#define N_REL   32
#define BLOCK   256
#define SCAN_TILE 2048

typedef __attribute__((ext_vector_type(8))) short bf16x8;   // 8 bf16 = 4 VGPRs
typedef __attribute__((ext_vector_type(4))) float f32x4;

__device__ __forceinline__ unsigned short f2bf(float f) {
    unsigned u = __float_as_uint(f);
    u += 0x7FFF + ((u >> 16) & 1);          // RNE
    return (unsigned short)(u >> 16);
}

// ---------------------------------------------------------------------------
// K0: cast node features fp32 -> bf16
// ---------------------------------------------------------------------------
__global__ void k_cast(const float* __restrict__ nf, unsigned short* __restrict__ xbf,
                       int total4) {
    int i = blockIdx.x * blockDim.x + threadIdx.x;
    if (i >= total4) return;
    float4 v = ((const float4*)nf)[i];
    ushort4 o;
    o.x = f2bf(v.x); o.y = f2bf(v.y); o.z = f2bf(v.z); o.w = f2bf(v.w);
    ((ushort4*)xbf)[i] = o;
}

// ---------------------------------------------------------------------------
// K1: relation weights -> bf16 in MFMA B-fragment layout (verified R5).
// ---------------------------------------------------------------------------
__global__ void k_relw(const float* __restrict__ basis,
                       const float* __restrict__ coeff,
                       unsigned short* __restrict__ Wsh) {
    int idx = blockIdx.x * blockDim.x + threadIdx.x;
    if (idx >= N_REL * N_F * N_F) return;
    int r  = idx >> 12;
    int io = idx & 4095;          // k*64 + n
    int k  = io >> 6;
    int n  = io & 63;
    float acc = 0.f;
#pragma unroll
    for (int b = 0; b < 30; ++b)
        acc += coeff[r * 30 + b] * basis[b * (N_F * N_F) + io];
    int ks = k >> 5, kk = k & 31;
    int nt = n >> 4, nl = n & 15;
    int lane = ((kk >> 3) << 4) | nl;
    int j    = kk & 7;
    Wsh[((((r * 2 + ks) * 4 + nt) * 64 + lane) << 3) + j] = f2bf(acc);
}

// ---------------------------------------------------------------------------
// Fused histograms: rel (32 bins, block-aggregated) + receiver (N bins)
// ---------------------------------------------------------------------------
__global__ void k_hist12(const int* __restrict__ rel, const int* __restrict__ rcv,
                         int* __restrict__ cnt1, int* __restrict__ cnt2, int E) {
    __shared__ int h[N_REL];
    if (threadIdx.x < N_REL) h[threadIdx.x] = 0;
    __syncthreads();
    int e = blockIdx.x * blockDim.x + threadIdx.x;
    if (e < E) {
        atomicAdd(&h[rel[e]], 1);
        atomicAdd(&cnt2[rcv[e]], 1);
    }
    __syncthreads();
    if (threadIdx.x < N_REL && h[threadIdx.x]) atomicAdd(&cnt1[threadIdx.x], h[threadIdx.x]);
}

// single-thread scan with 16-alignment; cur1 = running cursors; padcur = E
__global__ void k_scan1(const int* __restrict__ cnt1, int* __restrict__ base1,
                        int* __restrict__ cur1, int* __restrict__ padcur,
                        int Ppad, int E) {
    if (threadIdx.x == 0 && blockIdx.x == 0) {
        int acc = 0;
        for (int r = 0; r < N_REL; ++r) {
            base1[r] = acc;
            cur1[r]  = acc;
            acc += (cnt1[r] + 15) & ~15;
        }
        base1[N_REL] = Ppad;
        *padcur = E;
    }
}

__global__ void k_scatter1(const int* __restrict__ snd, const int* __restrict__ rcv,
                           const int* __restrict__ rel, int* __restrict__ cur1,
                           int* __restrict__ esrc, int* __restrict__ erecv, int E) {
    __shared__ int h[N_REL], hb[N_REL];
    if (threadIdx.x < N_REL) h[threadIdx.x] = 0;
    __syncthreads();
    int e = blockIdx.x * blockDim.x + threadIdx.x;
    int r = -1;
    if (e < E) { r = rel[e]; atomicAdd(&h[r], 1); }
    __syncthreads();
    if (threadIdx.x < N_REL && h[threadIdx.x])
        hb[threadIdx.x] = atomicAdd(&cur1[threadIdx.x], h[threadIdx.x]);
    __syncthreads();
    if (threadIdx.x < N_REL) h[threadIdx.x] = 0;
    __syncthreads();
    if (e < E) {
        int rank = atomicAdd(&h[r], 1);
        int pos  = hb[r] + rank;
        esrc[pos]  = snd[e];
        erecv[pos] = rcv[e];
    }
}

// ---------------------------------------------------------------------------
// Receiver scan (N bins) — 3-kernel scan
// ---------------------------------------------------------------------------
__global__ void k_scan_sums(const int* __restrict__ cur, int* __restrict__ part,
                            int nbins) {
    __shared__ int red[BLOCK];
    int base = blockIdx.x * SCAN_TILE;
    int s = 0;
    for (int i = threadIdx.x; i < SCAN_TILE; i += BLOCK) {
        int idx = base + i;
        s += (idx < nbins) ? cur[idx] : 0;
    }
    red[threadIdx.x] = s;
    __syncthreads();
    for (int off = BLOCK / 2; off > 0; off >>= 1) {
        if (threadIdx.x < off) red[threadIdx.x] += red[threadIdx.x + off];
        __syncthreads();
    }
    if (threadIdx.x == 0) part[blockIdx.x] = red[0];
}

__global__ void k_scan_part(int* __restrict__ part, int npart) {
    __shared__ int buf[BLOCK];
    __shared__ int carry;
    if (threadIdx.x == 0) carry = 0;
    __syncthreads();
    int nchunk = (npart + BLOCK - 1) / BLOCK;
    for (int c = 0; c < nchunk; ++c) {
        int i = c * BLOCK + threadIdx.x;
        int v = (i < npart) ? part[i] : 0;
        buf[threadIdx.x] = v;
        __syncthreads();
        for (int off = 1; off < BLOCK; off <<= 1) {
            int t = (threadIdx.x >= off) ? buf[threadIdx.x - off] : 0;
            __syncthreads();
            buf[threadIdx.x] += t;
            __syncthreads();
        }
        int incl = buf[threadIdx.x];
        int excl = incl - v + carry;
        if (i < npart) part[i] = excl;
        int chunk_sum = buf[BLOCK - 1];
        __syncthreads();
        if (threadIdx.x == 0) carry += chunk_sum;
        __syncthreads();
    }
}

__global__ void k_scan_apply(int* __restrict__ cur, const int* __restrict__ part,
                             int nbins) {
    __shared__ int buf[BLOCK];
    int base_t = blockIdx.x * SCAN_TILE + threadIdx.x * 8;
    int loc[8];
    int s = 0;
#pragma unroll
    for (int j = 0; j < 8; ++j) {
        int idx = base_t + j;
        int v = (idx < nbins) ? cur[idx] : 0;
        loc[j] = s;
        s += v;
    }
    buf[threadIdx.x] = s;
    __syncthreads();
    for (int off = 1; off < BLOCK; off <<= 1) {
        int t = (threadIdx.x >= off) ? buf[threadIdx.x - off] : 0;
        __syncthreads();
        buf[threadIdx.x] += t;
        __syncthreads();
    }
    int excl = buf[threadIdx.x] - s + part[blockIdx.x];
#pragma unroll
    for (int j = 0; j < 8; ++j) {
        int idx = base_t + j;
        if (idx < nbins) cur[idx] = loc[j] + excl;
    }
}

// perm[j] = receiver-sorted destination row of rel-sorted edge j.
// After this, cur2[n] == end pointer of receiver n's span. Pads -> [E, Ppad).
__global__ void k_scatter2(const int* __restrict__ erecv, int* __restrict__ cur2,
                           int* __restrict__ perm, int* __restrict__ padcur,
                           int P, int N) {
    int j = blockIdx.x * blockDim.x + threadIdx.x;
    if (j < P) {
        int d = erecv[j];
        int pos;
        if ((unsigned)d < (unsigned)N) pos = atomicAdd(&cur2[d], 1);
        else                           pos = atomicAdd(padcur, 1);
        perm[j] = pos;
    }
}

// tile -> relation (segments are 16-aligned, so each tile is single-rel)
__global__ void k_tilerel(const int* __restrict__ base1, unsigned char* __restrict__ trel,
                          int T) {
    int t = blockIdx.x * blockDim.x + threadIdx.x;
    if (t >= T) return;
    int p = t << 4;
    int r = 0;
#pragma unroll
    for (int i = 1; i < N_REL; ++i) r += (p >= base1[i]);
    trel[t] = (unsigned char)r;
}

// ---------------------------------------------------------------------------
// Phase A: per-tile GEMM -> bf16 edge rows scattered to receiver-sorted
// positions (via perm). No barriers, no atomics; wave-private LDS transpose.
// ---------------------------------------------------------------------------
__global__ void __launch_bounds__(BLOCK) k_gemm(const unsigned short* __restrict__ xbf,
                                                const int* __restrict__ esrc,
                                                const int* __restrict__ perm,
                                                const unsigned char* __restrict__ trel,
                                                const unsigned short* __restrict__ Wsh,
                                                unsigned short* __restrict__ eoutb,
                                                int T, int tpw) {
    __shared__ float ts[4][16 * 68];        // per-wave 16x64 transpose, stride 68
    const int tid  = threadIdx.x;
    const int lane = tid & 63;
    const int wave = tid >> 6;
    float* tb = ts[wave];

    const int gw = blockIdx.x * 4 + wave;
    const int t0 = gw * tpw;
    const int t1 = min(t0 + tpw, T);

    const int row = lane & 15;
    const int kg  = lane >> 4;
    const int rr  = lane >> 2;      // store-phase row
    const int ch  = lane & 3;       // store-phase 16-col chunk

    int curR = -1;
    bf16x8 wf[2][4];

    for (int t = t0; t < t1; ++t) {
        const int r = trel[t];
        if (r != curR) {
            curR = r;
#pragma unroll
            for (int ks = 0; ks < 2; ++ks)
#pragma unroll
                for (int nt = 0; nt < 4; ++nt)
                    wf[ks][nt] = *(const bf16x8*)(Wsh + ((((r * 2 + ks) * 4 + nt) * 64 + lane) << 3));
        }

        const int p  = (t << 4) + row;
        const int s  = esrc[p];
        const int pm = perm[p];
        const size_t xb = ((size_t)s << 6) + (kg << 3);
        bf16x8 a0 = *(const bf16x8*)(xbf + xb);
        bf16x8 a1 = *(const bf16x8*)(xbf + xb + 32);

        f32x4 acc[4];
#pragma unroll
        for (int nt = 0; nt < 4; ++nt) {
            acc[nt] = (f32x4){0.f, 0.f, 0.f, 0.f};
            acc[nt] = __builtin_amdgcn_mfma_f32_16x16x32_bf16(a0, wf[0][nt], acc[nt], 0, 0, 0);
            acc[nt] = __builtin_amdgcn_mfma_f32_16x16x32_bf16(a1, wf[1][nt], acc[nt], 0, 0, 0);
        }

        // C-layout (col=lane&15, row=kg*4+reg) -> LDS row-major
#pragma unroll
        for (int nt = 0; nt < 4; ++nt)
#pragma unroll
            for (int reg = 0; reg < 4; ++reg)
                tb[(kg * 4 + reg) * 68 + nt * 16 + (lane & 15)] = acc[nt][reg];

        asm volatile("s_waitcnt lgkmcnt(0)" ::: "memory");   // wave-local RAW

        const int pmr = __shfl(pm, rr);       // dest row of store-phase row

        const float* src = tb + rr * 68 + ch * 16;
        unsigned pk[8];
#pragma unroll
        for (int q = 0; q < 4; ++q) {
            float4 v = *(const float4*)(src + q * 4);
            pk[2 * q]     = (unsigned)f2bf(v.x) | ((unsigned)f2bf(v.y) << 16);
            pk[2 * q + 1] = (unsigned)f2bf(v.z) | ((unsigned)f2bf(v.w) << 16);
        }
        unsigned short* dst = eoutb + (size_t)pmr * 64 + ch * 16;
        uint4 v0; v0.x = pk[0]; v0.y = pk[1]; v0.z = pk[2]; v0.w = pk[3];
        uint4 v1; v1.x = pk[4]; v1.y = pk[5]; v1.z = pk[6]; v1.w = pk[7];
        *(uint4*)dst       = v0;
        *(uint4*)(dst + 8) = v1;
    }
}

// ---------------------------------------------------------------------------
// Phase B: wave per receiver, lane = feature. Rows are contiguous [st,en):
// pure streaming reads, 4 independent loads in flight, no indices, no
// atomics, no LDS. Fused deg-divide + fp32 self-loop + bias.
// ---------------------------------------------------------------------------
__global__ void __launch_bounds__(BLOCK) k_recv(const float* __restrict__ nf,
                                                const unsigned short* __restrict__ eoutb,
                                                const int* __restrict__ cur2,
                                                const float* __restrict__ selfw,
                                                const float* __restrict__ bias,
                                                float* __restrict__ out,
                                                int N, int rpw) {
    const int tid  = threadIdx.x;
    const int lane = tid & 63;
    const int wave = tid >> 6;
    const int gw   = blockIdx.x * 4 + wave;
    const int n0   = gw * rpw;
    const int n1   = min(n0 + rpw, N);
    if (n0 >= N) return;

    float swcol[N_F];
#pragma unroll
    for (int i = 0; i < N_F; ++i) swcol[i] = selfw[i * N_F + lane];
    const float bv = bias[lane];

    int st = (n0 == 0) ? 0 : cur2[n0 - 1];
    for (int n = n0; n < n1; ++n) {
        const int en = cur2[n];

        float acc = 0.f;
        int j = st;
        for (; j + 4 <= en; j += 4) {
            float a0 = __uint_as_float((unsigned)eoutb[(size_t)(j + 0) * 64 + lane] << 16);
            float a1 = __uint_as_float((unsigned)eoutb[(size_t)(j + 1) * 64 + lane] << 16);
            float a2 = __uint_as_float((unsigned)eoutb[(size_t)(j + 2) * 64 + lane] << 16);
            float a3 = __uint_as_float((unsigned)eoutb[(size_t)(j + 3) * 64 + lane] << 16);
            acc += (a0 + a1) + (a2 + a3);
        }
        for (; j < en; ++j)
            acc += __uint_as_float((unsigned)eoutb[(size_t)j * 64 + lane] << 16);

        const float4* xr = (const float4*)(nf + (size_t)n * N_F);
        float s0 = 0.f, s1 = 0.f, s2 = 0.f, s3 = 0.f;
#pragma unroll
        for (int q = 0; q < 16; ++q) {
            float4 xv = xr[q];                                // broadcast
            s0 = __builtin_fmaf(xv.x, swcol[4 * q + 0], s0);
            s1 = __builtin_fmaf(xv.y, swcol[4 * q + 1], s1);
            s2 = __builtin_fmaf(xv.z, swcol[4 * q + 2], s2);
            s3 = __builtin_fmaf(xv.w, swcol[4 * q + 3], s3);
        }

        float dg  = (float)(en - st);
        float inv = 1.f / (dg < 1.f ? 1.f : dg);
        out[(size_t)n * N_F + lane] = acc * inv + (s0 + s1) + (s2 + s3) + bv;
        st = en;
    }
}

// ---------------------------------------------------------------------------
extern "C" void kernel_launch(void* const* d_in, const int* in_sizes, int n_in,
                              void* d_out, int out_size, void* d_ws, size_t ws_size,
                              hipStream_t stream) {
    const float* nf    = (const float*)d_in[0];
    const int*   snd   = (const int*)  d_in[1];
    const int*   rcv   = (const int*)  d_in[2];
    const int*   rel   = (const int*)  d_in[3];
    const float* basis = (const float*)d_in[4];
    const float* coeff = (const float*)d_in[5];
    const float* selfw = (const float*)d_in[6];
    const float* bias  = (const float*)d_in[7];
    float*       out   = (float*)d_out;

    const int N = in_sizes[0] / N_F;                  // 100000
    const int E = in_sizes[1];                        // 1000000
    const int Ppad = (E + N_REL * 15 + 15) & ~15;     // padded rel-sorted length
    const int T    = Ppad >> 4;                       // total 16-edge tiles
    const int NPART = (N + SCAN_TILE - 1) / SCAN_TILE;

    // ws layout (eoutb first for 16B alignment of uint4 stores)
    unsigned short* eoutb = (unsigned short*)d_ws;                    // Ppad*64 bf16
    unsigned short* Wsh   = eoutb + (size_t)Ppad * N_F;               // 131072
    unsigned short* xbf   = Wsh + (size_t)N_REL * N_F * N_F;          // N*64
    int* base1  = (int*)(xbf + (size_t)N * N_F);                      // 33 (+pad)
    int* cur1   = base1 + 64;
    int* cnt1   = cur1 + 32;
    int* padcur = cnt1 + 32;
    int* part   = padcur + 32;                                        // NPART (<=64)
    int* cnt2   = part + 64;                                          // N  (becomes cur2)
    int* esrc   = cnt2 + N;                                           // Ppad
    int* erecv  = esrc + Ppad;                                        // Ppad
    int* perm   = erecv + Ppad;                                       // Ppad
    unsigned char* trel = (unsigned char*)(perm + Ppad);              // T

    hipMemsetAsync(cnt1, 0, 32 * sizeof(int), stream);
    hipMemsetAsync(cnt2, 0, (size_t)N * sizeof(int), stream);
    hipMemsetAsync(esrc, 0, (size_t)Ppad * sizeof(int), stream);      // pads -> node 0
    hipMemsetAsync(erecv, 0xFF, (size_t)Ppad * sizeof(int), stream);  // pads -> invalid

    k_cast<<<(N * N_F / 4 + BLOCK - 1) / BLOCK, BLOCK, 0, stream>>>(nf, xbf, N * N_F / 4);
    k_relw<<<(N_REL * N_F * N_F + BLOCK - 1) / BLOCK, BLOCK, 0, stream>>>(basis, coeff, Wsh);

    k_hist12<<<(E + BLOCK - 1) / BLOCK, BLOCK, 0, stream>>>(rel, rcv, cnt1, cnt2, E);
    k_scan1<<<1, 64, 0, stream>>>(cnt1, base1, cur1, padcur, Ppad, E);
    k_scatter1<<<(E + BLOCK - 1) / BLOCK, BLOCK, 0, stream>>>(snd, rcv, rel, cur1, esrc, erecv, E);

    k_scan_sums <<<NPART, BLOCK, 0, stream>>>(cnt2, part, N);
    k_scan_part <<<1,     BLOCK, 0, stream>>>(part, NPART);
    k_scan_apply<<<NPART, BLOCK, 0, stream>>>(cnt2, part, N);
    k_scatter2<<<(Ppad + BLOCK - 1) / BLOCK, BLOCK, 0, stream>>>(erecv, cnt2, perm, padcur, Ppad, N);

    k_tilerel<<<(T + BLOCK - 1) / BLOCK, BLOCK, 0, stream>>>(base1, trel, T);

    const int GEMM_BLOCKS = 512;                       // 2048 waves
    const int tpw = (T + GEMM_BLOCKS * 4 - 1) / (GEMM_BLOCKS * 4);
    k_gemm<<<GEMM_BLOCKS, BLOCK, 0, stream>>>(xbf, esrc, perm, trel, Wsh, eoutb, T, tpw);

    const int RECV_BLOCKS = 1024;                      // 4096 waves
    const int rpw = (N + RECV_BLOCKS * 4 - 1) / (RECV_BLOCKS * 4);
    k_recv<<<RECV_BLOCKS, BLOCK, 0, stream>>>(nf, eoutb, cnt2, selfw, bias, out, N, rpw);
}

// Round 8
// 433.597 us; speedup vs baseline: 2.4229x; 1.0265x over previous
//
#include <hip/hip_runtime.h>

#define N_F     64
#define N_REL   32
#define BLOCK   256
#define SCAN_TILE 2048

typedef __attribute__((ext_vector_type(8))) short bf16x8;   // 8 bf16 = 4 VGPRs
typedef __attribute__((ext_vector_type(4))) float f32x4;

__device__ __forceinline__ unsigned short f2bf(float f) {
    unsigned u = __float_as_uint(f);
    u += 0x7FFF + ((u >> 16) & 1);          // RNE
    return (unsigned short)(u >> 16);
}

// ---------------------------------------------------------------------------
// K0: cast node features fp32 -> bf16
// ---------------------------------------------------------------------------
__global__ void k_cast(const float* __restrict__ nf, unsigned short* __restrict__ xbf,
                       int total4) {
    int i = blockIdx.x * blockDim.x + threadIdx.x;
    if (i >= total4) return;
    float4 v = ((const float4*)nf)[i];
    ushort4 o;
    o.x = f2bf(v.x); o.y = f2bf(v.y); o.z = f2bf(v.z); o.w = f2bf(v.w);
    ((ushort4*)xbf)[i] = o;
}

// ---------------------------------------------------------------------------
// K1: relation weights -> bf16 in MFMA B-fragment layout (verified R5).
// ---------------------------------------------------------------------------
__global__ void k_relw(const float* __restrict__ basis,
                       const float* __restrict__ coeff,
                       unsigned short* __restrict__ Wsh) {
    int idx = blockIdx.x * blockDim.x + threadIdx.x;
    if (idx >= N_REL * N_F * N_F) return;
    int r  = idx >> 12;
    int io = idx & 4095;          // k*64 + n
    int k  = io >> 6;
    int n  = io & 63;
    float acc = 0.f;
#pragma unroll
    for (int b = 0; b < 30; ++b)
        acc += coeff[r * 30 + b] * basis[b * (N_F * N_F) + io];
    int ks = k >> 5, kk = k & 31;
    int nt = n >> 4, nl = n & 15;
    int lane = ((kk >> 3) << 4) | nl;
    int j    = kk & 7;
    Wsh[((((r * 2 + ks) * 4 + nt) * 64 + lane) << 3) + j] = f2bf(acc);
}

// ---------------------------------------------------------------------------
// Fused histograms: rel (32 bins, block-aggregated) + receiver (N bins)
// ---------------------------------------------------------------------------
__global__ void k_hist12(const int* __restrict__ rel, const int* __restrict__ rcv,
                         int* __restrict__ cnt1, int* __restrict__ cnt2, int E) {
    __shared__ int h[N_REL];
    if (threadIdx.x < N_REL) h[threadIdx.x] = 0;
    __syncthreads();
    int e = blockIdx.x * blockDim.x + threadIdx.x;
    if (e < E) {
        atomicAdd(&h[rel[e]], 1);
        atomicAdd(&cnt2[rcv[e]], 1);
    }
    __syncthreads();
    if (threadIdx.x < N_REL && h[threadIdx.x]) atomicAdd(&cnt1[threadIdx.x], h[threadIdx.x]);
}

// single-thread scan with 16-alignment over rel bins
__global__ void k_scan1(const int* __restrict__ cnt1, int* __restrict__ base1,
                        int* __restrict__ cur1, int Ppad) {
    if (threadIdx.x == 0 && blockIdx.x == 0) {
        int acc = 0;
        for (int r = 0; r < N_REL; ++r) {
            base1[r] = acc;
            cur1[r]  = acc;
            acc += (cnt1[r] + 15) & ~15;
        }
        base1[N_REL] = Ppad;
    }
}

// ---------------------------------------------------------------------------
// Receiver scan (N bins) — 3-kernel scan; cnt2 -> exclusive base pointers
// ---------------------------------------------------------------------------
__global__ void k_scan_sums(const int* __restrict__ cur, int* __restrict__ part,
                            int nbins) {
    __shared__ int red[BLOCK];
    int base = blockIdx.x * SCAN_TILE;
    int s = 0;
    for (int i = threadIdx.x; i < SCAN_TILE; i += BLOCK) {
        int idx = base + i;
        s += (idx < nbins) ? cur[idx] : 0;
    }
    red[threadIdx.x] = s;
    __syncthreads();
    for (int off = BLOCK / 2; off > 0; off >>= 1) {
        if (threadIdx.x < off) red[threadIdx.x] += red[threadIdx.x + off];
        __syncthreads();
    }
    if (threadIdx.x == 0) part[blockIdx.x] = red[0];
}

__global__ void k_scan_part(int* __restrict__ part, int npart) {
    __shared__ int buf[BLOCK];
    __shared__ int carry;
    if (threadIdx.x == 0) carry = 0;
    __syncthreads();
    int nchunk = (npart + BLOCK - 1) / BLOCK;
    for (int c = 0; c < nchunk; ++c) {
        int i = c * BLOCK + threadIdx.x;
        int v = (i < npart) ? part[i] : 0;
        buf[threadIdx.x] = v;
        __syncthreads();
        for (int off = 1; off < BLOCK; off <<= 1) {
            int t = (threadIdx.x >= off) ? buf[threadIdx.x - off] : 0;
            __syncthreads();
            buf[threadIdx.x] += t;
            __syncthreads();
        }
        int incl = buf[threadIdx.x];
        int excl = incl - v + carry;
        if (i < npart) part[i] = excl;
        int chunk_sum = buf[BLOCK - 1];
        __syncthreads();
        if (threadIdx.x == 0) carry += chunk_sum;
        __syncthreads();
    }
}

__global__ void k_scan_apply(int* __restrict__ cur, const int* __restrict__ part,
                             int nbins) {
    __shared__ int buf[BLOCK];
    int base_t = blockIdx.x * SCAN_TILE + threadIdx.x * 8;
    int loc[8];
    int s = 0;
#pragma unroll
    for (int j = 0; j < 8; ++j) {
        int idx = base_t + j;
        int v = (idx < nbins) ? cur[idx] : 0;
        loc[j] = s;
        s += v;
    }
    buf[threadIdx.x] = s;
    __syncthreads();
    for (int off = 1; off < BLOCK; off <<= 1) {
        int t = (threadIdx.x >= off) ? buf[threadIdx.x - off] : 0;
        __syncthreads();
        buf[threadIdx.x] += t;
        __syncthreads();
    }
    int excl = buf[threadIdx.x] - s + part[blockIdx.x];
#pragma unroll
    for (int j = 0; j < 8; ++j) {
        int idx = base_t + j;
        if (idx < nbins) cur[idx] = loc[j] + excl;
    }
}

// ---------------------------------------------------------------------------
// Fused scatter: pos1 = rel-sorted slot (block-aggregated cur1 atomics),
// pos2 = receiver-sorted row (per-edge cur2 atomic). esrc[pos1] = snd,
// perm[pos1] = pos2. After this, cur2[n] == end pointer of node n's span.
// ---------------------------------------------------------------------------
__global__ void k_scatter1(const int* __restrict__ snd, const int* __restrict__ rcv,
                           const int* __restrict__ rel, int* __restrict__ cur1,
                           int* __restrict__ cur2,
                           int* __restrict__ esrc, int* __restrict__ perm, int E) {
    __shared__ int h[N_REL], hb[N_REL];
    if (threadIdx.x < N_REL) h[threadIdx.x] = 0;
    __syncthreads();
    int e = blockIdx.x * blockDim.x + threadIdx.x;
    int r = -1;
    if (e < E) { r = rel[e]; atomicAdd(&h[r], 1); }
    __syncthreads();
    if (threadIdx.x < N_REL && h[threadIdx.x])
        hb[threadIdx.x] = atomicAdd(&cur1[threadIdx.x], h[threadIdx.x]);
    __syncthreads();
    if (threadIdx.x < N_REL) h[threadIdx.x] = 0;
    __syncthreads();
    if (e < E) {
        int rank = atomicAdd(&h[r], 1);
        int pos1 = hb[r] + rank;
        int pos2 = atomicAdd(&cur2[rcv[e]], 1);
        esrc[pos1] = snd[e];
        perm[pos1] = pos2;
    }
}

// tile -> relation (segments are 16-aligned, so each tile is single-rel)
__global__ void k_tilerel(const int* __restrict__ base1, unsigned char* __restrict__ trel,
                          int T) {
    int t = blockIdx.x * blockDim.x + threadIdx.x;
    if (t >= T) return;
    int p = t << 4;
    int r = 0;
#pragma unroll
    for (int i = 1; i < N_REL; ++i) r += (p >= base1[i]);
    trel[t] = (unsigned char)r;
}

// ---------------------------------------------------------------------------
// Phase A: per-tile GEMM -> bf16 edge rows scattered to receiver-sorted
// positions (via perm; pads perm=-1 -> dump row E). No barriers/atomics.
// ---------------------------------------------------------------------------
__global__ void __launch_bounds__(BLOCK) k_gemm(const unsigned short* __restrict__ xbf,
                                                const int* __restrict__ esrc,
                                                const int* __restrict__ perm,
                                                const unsigned char* __restrict__ trel,
                                                const unsigned short* __restrict__ Wsh,
                                                unsigned short* __restrict__ eoutb,
                                                int T, int tpw, int dumprow) {
    __shared__ float ts[4][16 * 68];        // per-wave 16x64 transpose, stride 68
    const int tid  = threadIdx.x;
    const int lane = tid & 63;
    const int wave = tid >> 6;
    float* tb = ts[wave];

    const int gw = blockIdx.x * 4 + wave;
    const int t0 = gw * tpw;
    const int t1 = min(t0 + tpw, T);

    const int row = lane & 15;
    const int kg  = lane >> 4;
    const int rr  = lane >> 2;      // store-phase row
    const int ch  = lane & 3;       // store-phase 16-col chunk

    int curR = -1;
    bf16x8 wf[2][4];

    for (int t = t0; t < t1; ++t) {
        const int r = trel[t];
        if (r != curR) {
            curR = r;
#pragma unroll
            for (int ks = 0; ks < 2; ++ks)
#pragma unroll
                for (int nt = 0; nt < 4; ++nt)
                    wf[ks][nt] = *(const bf16x8*)(Wsh + ((((r * 2 + ks) * 4 + nt) * 64 + lane) << 3));
        }

        const int p  = (t << 4) + row;
        const int s  = esrc[p];
        const int pm = perm[p];
        const size_t xb = ((size_t)s << 6) + (kg << 3);
        bf16x8 a0 = *(const bf16x8*)(xbf + xb);
        bf16x8 a1 = *(const bf16x8*)(xbf + xb + 32);

        f32x4 acc[4];
#pragma unroll
        for (int nt = 0; nt < 4; ++nt) {
            acc[nt] = (f32x4){0.f, 0.f, 0.f, 0.f};
            acc[nt] = __builtin_amdgcn_mfma_f32_16x16x32_bf16(a0, wf[0][nt], acc[nt], 0, 0, 0);
            acc[nt] = __builtin_amdgcn_mfma_f32_16x16x32_bf16(a1, wf[1][nt], acc[nt], 0, 0, 0);
        }

        // C-layout (col=lane&15, row=kg*4+reg) -> LDS row-major
#pragma unroll
        for (int nt = 0; nt < 4; ++nt)
#pragma unroll
            for (int reg = 0; reg < 4; ++reg)
                tb[(kg * 4 + reg) * 68 + nt * 16 + (lane & 15)] = acc[nt][reg];

        asm volatile("s_waitcnt lgkmcnt(0)" ::: "memory");   // wave-local RAW

        int pmr = __shfl(pm, rr);             // dest row of store-phase row
        pmr = (pmr < 0) ? dumprow : pmr;      // pad rows -> dump

        const float* src = tb + rr * 68 + ch * 16;
        unsigned pk[8];
#pragma unroll
        for (int q = 0; q < 4; ++q) {
            float4 v = *(const float4*)(src + q * 4);
            pk[2 * q]     = (unsigned)f2bf(v.x) | ((unsigned)f2bf(v.y) << 16);
            pk[2 * q + 1] = (unsigned)f2bf(v.z) | ((unsigned)f2bf(v.w) << 16);
        }
        unsigned short* dst = eoutb + (size_t)pmr * 64 + ch * 16;
        uint4 v0; v0.x = pk[0]; v0.y = pk[1]; v0.z = pk[2]; v0.w = pk[3];
        uint4 v1; v1.x = pk[4]; v1.y = pk[5]; v1.z = pk[6]; v1.w = pk[7];
        *(uint4*)dst       = v0;
        *(uint4*)(dst + 8) = v1;
    }
}

// ---------------------------------------------------------------------------
// Phase B: wave per node, 8-rows-per-load layout: lane = (rowgrp g = lane>>3,
// chunk c = lane&7). One uint4 load ingests 8 bf16; a wave reads 8 rows
// (1 KB) per load instruction. Butterfly reduce over g, transpose back to
// lane=feature, fused deg-divide + fp32 self-loop + bias.
// ---------------------------------------------------------------------------
__global__ void __launch_bounds__(BLOCK) k_recv(const float* __restrict__ nf,
                                                const unsigned short* __restrict__ eoutb,
                                                const int* __restrict__ cur2,
                                                const float* __restrict__ selfw,
                                                const float* __restrict__ bias,
                                                float* __restrict__ out,
                                                int N, int rpw) {
    const int tid  = threadIdx.x;
    const int lane = tid & 63;
    const int wave = tid >> 6;
    const int gw   = blockIdx.x * 4 + wave;
    const int n0   = gw * rpw;
    const int n1   = min(n0 + rpw, N);
    if (n0 >= N) return;

    const int g = lane >> 3;      // row group within 8-row batch
    const int c = lane & 7;       // feature chunk (8 features)

    float swcol[N_F];
#pragma unroll
    for (int i = 0; i < N_F; ++i) swcol[i] = selfw[i * N_F + lane];
    const float bv = bias[lane];

    int st = (n0 == 0) ? 0 : cur2[n0 - 1];
    for (int n = n0; n < n1; ++n) {
        const int en = cur2[n];

        float a[8];
#pragma unroll
        for (int e = 0; e < 8; ++e) a[e] = 0.f;

        for (int j = st; j < en; j += 8) {
            const int row = j + g;   // overread past en stays in eoutb pad rows
            uint4 u = *(const uint4*)(eoutb + ((size_t)row << 6) + (c << 3));
            if (row < en) {
                a[0] += __uint_as_float(u.x << 16);
                a[1] += __uint_as_float(u.x & 0xFFFF0000u);
                a[2] += __uint_as_float(u.y << 16);
                a[3] += __uint_as_float(u.y & 0xFFFF0000u);
                a[4] += __uint_as_float(u.z << 16);
                a[5] += __uint_as_float(u.z & 0xFFFF0000u);
                a[6] += __uint_as_float(u.w << 16);
                a[7] += __uint_as_float(u.w & 0xFFFF0000u);
            }
        }

        // reduce over the 8 row groups (lanes with same c)
#pragma unroll
        for (int off = 8; off < 64; off <<= 1)
#pragma unroll
            for (int e = 0; e < 8; ++e)
                a[e] += __shfl_xor(a[e], off);

        // transpose to lane = feature: feature `lane` = chunk lane>>3, elem lane&7
        const int src = lane >> 3;
        float t[8];
#pragma unroll
        for (int e = 0; e < 8; ++e) t[e] = __shfl(a[e], src);
        const int sel = lane & 7;
        float agg = t[0];
#pragma unroll
        for (int e = 1; e < 8; ++e) agg = (sel == e) ? t[e] : agg;

        const float4* xr = (const float4*)(nf + (size_t)n * N_F);
        float s0 = 0.f, s1 = 0.f, s2 = 0.f, s3 = 0.f;
#pragma unroll
        for (int q = 0; q < 16; ++q) {
            float4 xv = xr[q];                                // broadcast
            s0 = __builtin_fmaf(xv.x, swcol[4 * q + 0], s0);
            s1 = __builtin_fmaf(xv.y, swcol[4 * q + 1], s1);
            s2 = __builtin_fmaf(xv.z, swcol[4 * q + 2], s2);
            s3 = __builtin_fmaf(xv.w, swcol[4 * q + 3], s3);
        }

        float dg  = (float)(en - st);
        float inv = 1.f / (dg < 1.f ? 1.f : dg);
        out[(size_t)n * N_F + lane] = agg * inv + (s0 + s1) + (s2 + s3) + bv;
        st = en;
    }
}

// ---------------------------------------------------------------------------
extern "C" void kernel_launch(void* const* d_in, const int* in_sizes, int n_in,
                              void* d_out, int out_size, void* d_ws, size_t ws_size,
                              hipStream_t stream) {
    const float* nf    = (const float*)d_in[0];
    const int*   snd   = (const int*)  d_in[1];
    const int*   rcv   = (const int*)  d_in[2];
    const int*   rel   = (const int*)  d_in[3];
    const float* basis = (const float*)d_in[4];
    const float* coeff = (const float*)d_in[5];
    const float* selfw = (const float*)d_in[6];
    const float* bias  = (const float*)d_in[7];
    float*       out   = (float*)d_out;

    const int N = in_sizes[0] / N_F;                  // 100000
    const int E = in_sizes[1];                        // 1000000
    const int Ppad = (E + N_REL * 15 + 15) & ~15;     // padded rel-sorted length
    const int T    = Ppad >> 4;                       // total 16-edge tiles
    const int NPART = (N + SCAN_TILE - 1) / SCAN_TILE;

    // ws layout (eoutb first for 16B alignment of uint4 stores)
    unsigned short* eoutb = (unsigned short*)d_ws;                    // Ppad*64 bf16
    unsigned short* Wsh   = eoutb + (size_t)Ppad * N_F;               // 131072
    unsigned short* xbf   = Wsh + (size_t)N_REL * N_F * N_F;          // N*64
    int* base1  = (int*)(xbf + (size_t)N * N_F);                      // 33 (+pad)
    int* cur1   = base1 + 64;
    int* cnt1   = cur1 + 32;
    int* part   = cnt1 + 32;                                          // NPART (<=64)
    int* cnt2   = part + 64;                                          // N (base -> end ptrs)
    int* esrc   = cnt2 + N;                                           // Ppad
    int* perm   = esrc + Ppad;                                        // Ppad
    unsigned char* trel = (unsigned char*)(perm + Ppad);              // T

    hipMemsetAsync(cnt1, 0, 32 * sizeof(int), stream);
    hipMemsetAsync(cnt2, 0, (size_t)N * sizeof(int), stream);
    hipMemsetAsync(esrc, 0, (size_t)Ppad * sizeof(int), stream);      // pads -> node 0
    hipMemsetAsync(perm, 0xFF, (size_t)Ppad * sizeof(int), stream);   // pads -> -1

    k_cast<<<(N * N_F / 4 + BLOCK - 1) / BLOCK, BLOCK, 0, stream>>>(nf, xbf, N * N_F / 4);
    k_relw<<<(N_REL * N_F * N_F + BLOCK - 1) / BLOCK, BLOCK, 0, stream>>>(basis, coeff, Wsh);

    k_hist12<<<(E + BLOCK - 1) / BLOCK, BLOCK, 0, stream>>>(rel, rcv, cnt1, cnt2, E);
    k_scan1<<<1, 64, 0, stream>>>(cnt1, base1, cur1, Ppad);
    k_scan_sums <<<NPART, BLOCK, 0, stream>>>(cnt2, part, N);
    k_scan_part <<<1,     BLOCK, 0, stream>>>(part, NPART);
    k_scan_apply<<<NPART, BLOCK, 0, stream>>>(cnt2, part, N);

    k_scatter1<<<(E + BLOCK - 1) / BLOCK, BLOCK, 0, stream>>>(snd, rcv, rel, cur1, cnt2,
                                                              esrc, perm, E);

    k_tilerel<<<(T + BLOCK - 1) / BLOCK, BLOCK, 0, stream>>>(base1, trel, T);

    const int GEMM_BLOCKS = 1024;                      // 4096 waves
    const int tpw = (T + GEMM_BLOCKS * 4 - 1) / (GEMM_BLOCKS * 4);
    k_gemm<<<GEMM_BLOCKS, BLOCK, 0, stream>>>(xbf, esrc, perm, trel, Wsh, eoutb, T, tpw, E);

    const int RECV_BLOCKS = 2048;                      // 8192 waves
    const int rpw = (N + RECV_BLOCKS * 4 - 1) / (RECV_BLOCKS * 4);
    k_recv<<<RECV_BLOCKS, BLOCK, 0, stream>>>(nf, eoutb, cnt2, selfw, bias, out, N, rpw);
}

// Round 10
// 372.199 us; speedup vs baseline: 2.8225x; 1.1650x over previous
//
#include <hip/hip_runtime.h>

#define N_F     64
#define N_REL   32
#define BLOCK   256
#define SCAN_TILE 2048

typedef __attribute__((ext_vector_type(8))) short bf16x8;   // 8 bf16 = 4 VGPRs
typedef __attribute__((ext_vector_type(4))) float f32x4;

__device__ __forceinline__ unsigned short f2bf(float f) {
    unsigned u = __float_as_uint(f);
    u += 0x7FFF + ((u >> 16) & 1);          // RNE
    return (unsigned short)(u >> 16);
}

// ---------------------------------------------------------------------------
// K-pre: region-branched fusion of cast | relw | hist12
// ---------------------------------------------------------------------------
__global__ void __launch_bounds__(BLOCK) k_pre(const float* __restrict__ nf,
                                               const int* __restrict__ rel,
                                               const int* __restrict__ rcv,
                                               const float* __restrict__ basis,
                                               const float* __restrict__ coeff,
                                               unsigned short* __restrict__ xbf,
                                               unsigned short* __restrict__ Wsh,
                                               int* __restrict__ cnt1,
                                               int* __restrict__ cnt2,
                                               int E, int total4,
                                               int nbCast, int nbRelw) {
    const int bid = blockIdx.x;
    if (bid < nbCast) {
        int i = bid * BLOCK + threadIdx.x;
        if (i < total4) {
            float4 v = ((const float4*)nf)[i];
            ushort4 o;
            o.x = f2bf(v.x); o.y = f2bf(v.y); o.z = f2bf(v.z); o.w = f2bf(v.w);
            ((ushort4*)xbf)[i] = o;
        }
    } else if (bid < nbCast + nbRelw) {
        int idx = (bid - nbCast) * BLOCK + threadIdx.x;
        if (idx < N_REL * N_F * N_F) {
            int r  = idx >> 12;
            int io = idx & 4095;          // k*64 + n
            int k  = io >> 6;
            int n  = io & 63;
            float acc = 0.f;
#pragma unroll
            for (int b = 0; b < 30; ++b)
                acc += coeff[r * 30 + b] * basis[b * (N_F * N_F) + io];
            int ks = k >> 5, kk = k & 31;
            int nt = n >> 4, nl = n & 15;
            int lane = ((kk >> 3) << 4) | nl;
            int j    = kk & 7;
            Wsh[((((r * 2 + ks) * 4 + nt) * 64 + lane) << 3) + j] = f2bf(acc);
        }
    } else {
        __shared__ int h[N_REL];
        if (threadIdx.x < N_REL) h[threadIdx.x] = 0;
        __syncthreads();
        int e = (bid - nbCast - nbRelw) * BLOCK + threadIdx.x;
        if (e < E) {
            atomicAdd(&h[rel[e]], 1);
            atomicAdd(&cnt2[rcv[e]], 1);
        }
        __syncthreads();
        if (threadIdx.x < N_REL && h[threadIdx.x])
            atomicAdd(&cnt1[threadIdx.x], h[threadIdx.x]);
    }
}

// ---------------------------------------------------------------------------
// Receiver scan stage 1: per-tile sums
// ---------------------------------------------------------------------------
__global__ void k_scan_sums(const int* __restrict__ cur, int* __restrict__ part,
                            int nbins) {
    __shared__ int red[BLOCK];
    int base = blockIdx.x * SCAN_TILE;
    int s = 0;
    for (int i = threadIdx.x; i < SCAN_TILE; i += BLOCK) {
        int idx = base + i;
        s += (idx < nbins) ? cur[idx] : 0;
    }
    red[threadIdx.x] = s;
    __syncthreads();
    for (int off = BLOCK / 2; off > 0; off >>= 1) {
        if (threadIdx.x < off) red[threadIdx.x] += red[threadIdx.x + off];
        __syncthreads();
    }
    if (threadIdx.x == 0) part[blockIdx.x] = red[0];
}

// ---------------------------------------------------------------------------
// Single-block middle stage: excl-scan of tile sums (npart<=256) + rel-bin
// scan (16-aligned) + pad-slot init (esrc=0, perm=-1) INCLUDING the tail
// [actual_total, Ppad) -- the R9 fault was the uninitialized tail.
// ---------------------------------------------------------------------------
__global__ void k_scan_mid(const int* __restrict__ cnt1, int* __restrict__ base1,
                           int* __restrict__ cur1, int* __restrict__ part,
                           int* __restrict__ esrc, int* __restrict__ perm,
                           int npart, int Ppad) {
    __shared__ int buf[BLOCK];
    __shared__ int sbase[N_REL + 1];
    __shared__ int stotal;
    const int tid = threadIdx.x;

    int v = (tid < npart) ? part[tid] : 0;
    buf[tid] = v;
    __syncthreads();
    for (int off = 1; off < BLOCK; off <<= 1) {
        int t = (tid >= off) ? buf[tid - off] : 0;
        __syncthreads();
        buf[tid] += t;
        __syncthreads();
    }
    if (tid < npart) part[tid] = buf[tid] - v;

    if (tid == 0) {
        int acc = 0;
        for (int r = 0; r < N_REL; ++r) {
            base1[r] = acc;
            cur1[r]  = acc;
            sbase[r] = acc;
            acc += (cnt1[r] + 15) & ~15;
        }
        base1[N_REL] = Ppad;
        sbase[N_REL] = Ppad;
        stotal = acc;                  // actual padded total (<= Ppad)
    }
    __syncthreads();

    // intra-bin pad slots
    for (int i = tid; i < N_REL * 16; i += BLOCK) {
        int r = i >> 4, o = i & 15;
        int c  = cnt1[r];
        int p0 = sbase[r] + c;
        int p1 = sbase[r] + ((c + 15) & ~15);
        int p  = p0 + o;
        if (p < p1) { perm[p] = -1; esrc[p] = 0; }
    }
    // tail [actual_total, Ppad)
    for (int p = stotal + tid; p < Ppad; p += BLOCK) {
        perm[p] = -1; esrc[p] = 0;
    }
}

// ---------------------------------------------------------------------------
// Receiver scan stage 3 (+ fused tile->relation table)
// ---------------------------------------------------------------------------
__global__ void k_scan_apply_tile(int* __restrict__ cur, const int* __restrict__ part,
                                  const int* __restrict__ base1,
                                  unsigned char* __restrict__ trel,
                                  int nbins, int npart, int T) {
    if ((int)blockIdx.x >= npart) {
        int t = (blockIdx.x - npart) * BLOCK + threadIdx.x;
        if (t < T) {
            int p = t << 4;
            int r = 0;
#pragma unroll
            for (int i = 1; i < N_REL; ++i) r += (p >= base1[i]);
            trel[t] = (unsigned char)r;
        }
        return;
    }
    __shared__ int buf[BLOCK];
    int base_t = blockIdx.x * SCAN_TILE + threadIdx.x * 8;
    int loc[8];
    int s = 0;
#pragma unroll
    for (int j = 0; j < 8; ++j) {
        int idx = base_t + j;
        int v = (idx < nbins) ? cur[idx] : 0;
        loc[j] = s;
        s += v;
    }
    buf[threadIdx.x] = s;
    __syncthreads();
    for (int off = 1; off < BLOCK; off <<= 1) {
        int t = (threadIdx.x >= off) ? buf[threadIdx.x - off] : 0;
        __syncthreads();
        buf[threadIdx.x] += t;
        __syncthreads();
    }
    int excl = buf[threadIdx.x] - s + part[blockIdx.x];
#pragma unroll
    for (int j = 0; j < 8; ++j) {
        int idx = base_t + j;
        if (idx < nbins) cur[idx] = loc[j] + excl;
    }
}

// ---------------------------------------------------------------------------
// Fused scatter: pos1 = rel-sorted slot, pos2 = receiver-sorted row.
// After this, cur2[n] == end pointer of node n's span.
// ---------------------------------------------------------------------------
__global__ void k_scatter1(const int* __restrict__ snd, const int* __restrict__ rcv,
                           const int* __restrict__ rel, int* __restrict__ cur1,
                           int* __restrict__ cur2,
                           int* __restrict__ esrc, int* __restrict__ perm, int E) {
    __shared__ int h[N_REL], hb[N_REL];
    if (threadIdx.x < N_REL) h[threadIdx.x] = 0;
    __syncthreads();
    int e = blockIdx.x * blockDim.x + threadIdx.x;
    int r = -1;
    if (e < E) { r = rel[e]; atomicAdd(&h[r], 1); }
    __syncthreads();
    if (threadIdx.x < N_REL && h[threadIdx.x])
        hb[threadIdx.x] = atomicAdd(&cur1[threadIdx.x], h[threadIdx.x]);
    __syncthreads();
    if (threadIdx.x < N_REL) h[threadIdx.x] = 0;
    __syncthreads();
    if (e < E) {
        int rank = atomicAdd(&h[r], 1);
        int pos1 = hb[r] + rank;
        int pos2 = atomicAdd(&cur2[rcv[e]], 1);
        esrc[pos1] = snd[e];
        perm[pos1] = pos2;
    }
}

// ---------------------------------------------------------------------------
// Phase A: per-tile GEMM -> bf16 edge rows at receiver-sorted positions.
// 1-deep prefetch of next tile's esrc/perm. No barriers/atomics.
// ---------------------------------------------------------------------------
__global__ void __launch_bounds__(BLOCK) k_gemm(const unsigned short* __restrict__ xbf,
                                                const int* __restrict__ esrc,
                                                const int* __restrict__ perm,
                                                const unsigned char* __restrict__ trel,
                                                const unsigned short* __restrict__ Wsh,
                                                unsigned short* __restrict__ eoutb,
                                                int T, int tpw, int dumprow) {
    __shared__ float ts[4][16 * 68];        // per-wave 16x64 transpose, stride 68
    const int tid  = threadIdx.x;
    const int lane = tid & 63;
    const int wave = tid >> 6;
    float* tb = ts[wave];

    const int gw = blockIdx.x * 4 + wave;
    const int t0 = gw * tpw;
    const int t1 = min(t0 + tpw, T);
    if (t0 >= T) return;

    const int row = lane & 15;
    const int kg  = lane >> 4;
    const int rr  = lane >> 2;      // store-phase row
    const int ch  = lane & 3;       // store-phase 16-col chunk

    int curR = -1;
    bf16x8 wf[2][4];

    int s_cur  = esrc[(t0 << 4) + row];
    int pm_cur = perm[(t0 << 4) + row];

    for (int t = t0; t < t1; ++t) {
        int s_nxt = 0, pm_nxt = -1;
        if (t + 1 < t1) {
            s_nxt  = esrc[((t + 1) << 4) + row];
            pm_nxt = perm[((t + 1) << 4) + row];
        }

        const int r = trel[t];
        if (r != curR) {
            curR = r;
#pragma unroll
            for (int ks = 0; ks < 2; ++ks)
#pragma unroll
                for (int nt = 0; nt < 4; ++nt)
                    wf[ks][nt] = *(const bf16x8*)(Wsh + ((((r * 2 + ks) * 4 + nt) * 64 + lane) << 3));
        }

        const size_t xb = ((size_t)s_cur << 6) + (kg << 3);
        bf16x8 a0 = *(const bf16x8*)(xbf + xb);
        bf16x8 a1 = *(const bf16x8*)(xbf + xb + 32);

        f32x4 acc[4];
#pragma unroll
        for (int nt = 0; nt < 4; ++nt) {
            acc[nt] = (f32x4){0.f, 0.f, 0.f, 0.f};
            acc[nt] = __builtin_amdgcn_mfma_f32_16x16x32_bf16(a0, wf[0][nt], acc[nt], 0, 0, 0);
            acc[nt] = __builtin_amdgcn_mfma_f32_16x16x32_bf16(a1, wf[1][nt], acc[nt], 0, 0, 0);
        }

        // C-layout (col=lane&15, row=kg*4+reg) -> LDS row-major
#pragma unroll
        for (int nt = 0; nt < 4; ++nt)
#pragma unroll
            for (int reg = 0; reg < 4; ++reg)
                tb[(kg * 4 + reg) * 68 + nt * 16 + (lane & 15)] = acc[nt][reg];

        asm volatile("s_waitcnt lgkmcnt(0)" ::: "memory");   // wave-local RAW

        int pmr = __shfl(pm_cur, rr);         // dest row of store-phase row
        pmr = (pmr < 0) ? dumprow : pmr;      // pad rows -> dump

        const float* src = tb + rr * 68 + ch * 16;
        unsigned pk[8];
#pragma unroll
        for (int q = 0; q < 4; ++q) {
            float4 v = *(const float4*)(src + q * 4);
            pk[2 * q]     = (unsigned)f2bf(v.x) | ((unsigned)f2bf(v.y) << 16);
            pk[2 * q + 1] = (unsigned)f2bf(v.z) | ((unsigned)f2bf(v.w) << 16);
        }
        unsigned short* dst = eoutb + (size_t)pmr * 64 + ch * 16;
        uint4 v0; v0.x = pk[0]; v0.y = pk[1]; v0.z = pk[2]; v0.w = pk[3];
        uint4 v1; v1.x = pk[4]; v1.y = pk[5]; v1.z = pk[6]; v1.w = pk[7];
        *(uint4*)dst       = v0;
        *(uint4*)(dst + 8) = v1;

        s_cur = s_nxt; pm_cur = pm_nxt;
    }
}

// ---------------------------------------------------------------------------
// Phase B: wave per node. 2-rows-per-load layout (g = lane>>5 row parity,
// c = lane&31 feat pair; one dword = 2 bf16, wave = 256 B/load). Reduction =
// 1 shfl_xor + 2 redistribution shfls + select. cur2 spans prefetched into
// lanes. Self-loop from bf16 xbf (8 broadcast uint4). No atomics/LDS.
// ---------------------------------------------------------------------------
__global__ void __launch_bounds__(BLOCK) k_recv(const unsigned short* __restrict__ xbf,
                                                const unsigned short* __restrict__ eoutb,
                                                const int* __restrict__ cur2,
                                                const float* __restrict__ selfw,
                                                const float* __restrict__ bias,
                                                float* __restrict__ out,
                                                int N, int rpw) {
    const int tid  = threadIdx.x;
    const int lane = tid & 63;
    const int wave = tid >> 6;
    const int gw   = blockIdx.x * 4 + wave;
    const int n0   = gw * rpw;
    const int n1   = min(n0 + rpw, N);
    if (n0 >= N) return;

    const int g = lane >> 5;        // row parity
    const int c = lane & 31;        // feat-pair index (feats 2c, 2c+1)

    float swcol[N_F];
#pragma unroll
    for (int i = 0; i < N_F; ++i) swcol[i] = selfw[i * N_F + lane];
    const float bv = bias[lane];

    // prefetch span boundaries: lane l holds cur2[n0-1+l]
    int bidx = n0 - 1 + lane;
    int bnd  = 0;
    if (bidx >= 0 && bidx < N && lane <= (n1 - n0)) bnd = cur2[bidx];

    for (int n = n0; n < n1; ++n) {
        const int li = n - n0;
        const int st = __shfl(bnd, li);
        const int en = __shfl(bnd, li + 1);

        float a0 = 0.f, a1 = 0.f;
        int j = st;
        for (; j + 4 <= en; j += 4) {
            unsigned u0 = *(const unsigned*)(eoutb + ((size_t)(j + g)     << 6) + (c << 1));
            unsigned u1 = *(const unsigned*)(eoutb + ((size_t)(j + 2 + g) << 6) + (c << 1));
            a0 += __uint_as_float(u0 << 16) + __uint_as_float(u1 << 16);
            a1 += __uint_as_float(u0 & 0xFFFF0000u) + __uint_as_float(u1 & 0xFFFF0000u);
        }
        for (; j < en; j += 2) {
            int row = j + g;        // overread row <= en < Ppad: safe, masked
            unsigned u = *(const unsigned*)(eoutb + ((size_t)row << 6) + (c << 1));
            if (row < en) {
                a0 += __uint_as_float(u << 16);
                a1 += __uint_as_float(u & 0xFFFF0000u);
            }
        }
        a0 += __shfl_xor(a0, 32);
        a1 += __shfl_xor(a1, 32);
        float v0 = __shfl(a0, lane >> 1);
        float v1 = __shfl(a1, lane >> 1);
        float agg = (lane & 1) ? v1 : v0;

        // self-loop from bf16 x (broadcast uint4 = 8 feats)
        const uint4* xr = (const uint4*)(xbf + ((size_t)n << 6));
        float s0 = 0.f, s1 = 0.f, s2 = 0.f, s3 = 0.f;
#pragma unroll
        for (int q = 0; q < 8; ++q) {
            uint4 u = xr[q];
            float x0 = __uint_as_float(u.x << 16);
            float x1 = __uint_as_float(u.x & 0xFFFF0000u);
            float x2 = __uint_as_float(u.y << 16);
            float x3 = __uint_as_float(u.y & 0xFFFF0000u);
            float x4 = __uint_as_float(u.z << 16);
            float x5 = __uint_as_float(u.z & 0xFFFF0000u);
            float x6 = __uint_as_float(u.w << 16);
            float x7 = __uint_as_float(u.w & 0xFFFF0000u);
            s0 = __builtin_fmaf(x0, swcol[8 * q + 0], s0);
            s1 = __builtin_fmaf(x1, swcol[8 * q + 1], s1);
            s2 = __builtin_fmaf(x2, swcol[8 * q + 2], s2);
            s3 = __builtin_fmaf(x3, swcol[8 * q + 3], s3);
            s0 = __builtin_fmaf(x4, swcol[8 * q + 4], s0);
            s1 = __builtin_fmaf(x5, swcol[8 * q + 5], s1);
            s2 = __builtin_fmaf(x6, swcol[8 * q + 6], s2);
            s3 = __builtin_fmaf(x7, swcol[8 * q + 7], s3);
        }

        float dg  = (float)(en - st);
        float inv = 1.f / (dg < 1.f ? 1.f : dg);
        out[(size_t)n * N_F + lane] = agg * inv + (s0 + s1) + (s2 + s3) + bv;
    }
}

// ---------------------------------------------------------------------------
extern "C" void kernel_launch(void* const* d_in, const int* in_sizes, int n_in,
                              void* d_out, int out_size, void* d_ws, size_t ws_size,
                              hipStream_t stream) {
    const float* nf    = (const float*)d_in[0];
    const int*   snd   = (const int*)  d_in[1];
    const int*   rcv   = (const int*)  d_in[2];
    const int*   rel   = (const int*)  d_in[3];
    const float* basis = (const float*)d_in[4];
    const float* coeff = (const float*)d_in[5];
    const float* selfw = (const float*)d_in[6];
    const float* bias  = (const float*)d_in[7];
    float*       out   = (float*)d_out;

    const int N = in_sizes[0] / N_F;                  // 100000
    const int E = in_sizes[1];                        // 1000000
    const int Ppad = (E + N_REL * 15 + 15) & ~15;     // padded rel-sorted length
    const int T    = Ppad >> 4;                       // total 16-edge tiles
    const int NPART = (N + SCAN_TILE - 1) / SCAN_TILE;
    const int total4 = N * N_F / 4;

    // ws layout
    unsigned short* eoutb = (unsigned short*)d_ws;                    // Ppad*64 bf16
    unsigned short* Wsh   = eoutb + (size_t)Ppad * N_F;               // 131072
    unsigned short* xbf   = Wsh + (size_t)N_REL * N_F * N_F;          // N*64
    int* base1 = (int*)(xbf + (size_t)N * N_F);                       // 64
    int* cur1  = base1 + 64;                                          // 32
    int* part  = cur1 + 32;                                           // NPART (<=256)
    int* cnt1  = part + 256;                                          // 32   } one memset
    int* cnt2  = cnt1 + 32;                                           // N    }
    int* esrc  = cnt2 + N;                                            // Ppad
    int* perm  = esrc + Ppad;                                         // Ppad
    unsigned char* trel = (unsigned char*)(perm + Ppad);              // T

    hipMemsetAsync(cnt1, 0, (size_t)(32 + N) * sizeof(int), stream);

    const int NB_CAST = (total4 + BLOCK - 1) / BLOCK;
    const int NB_RELW = (N_REL * N_F * N_F + BLOCK - 1) / BLOCK;
    const int NB_HIST = (E + BLOCK - 1) / BLOCK;
    k_pre<<<NB_CAST + NB_RELW + NB_HIST, BLOCK, 0, stream>>>(
        nf, rel, rcv, basis, coeff, xbf, Wsh, cnt1, cnt2, E, total4, NB_CAST, NB_RELW);

    k_scan_sums<<<NPART, BLOCK, 0, stream>>>(cnt2, part, N);
    k_scan_mid <<<1,     BLOCK, 0, stream>>>(cnt1, base1, cur1, part, esrc, perm, NPART, Ppad);

    const int NB_TREL = (T + BLOCK - 1) / BLOCK;
    k_scan_apply_tile<<<NPART + NB_TREL, BLOCK, 0, stream>>>(cnt2, part, base1, trel, N, NPART, T);

    k_scatter1<<<(E + BLOCK - 1) / BLOCK, BLOCK, 0, stream>>>(snd, rcv, rel, cur1, cnt2,
                                                              esrc, perm, E);

    const int GEMM_BLOCKS = 1024;                      // 4096 waves
    const int tpw = (T + GEMM_BLOCKS * 4 - 1) / (GEMM_BLOCKS * 4);
    k_gemm<<<GEMM_BLOCKS, BLOCK, 0, stream>>>(xbf, esrc, perm, trel, Wsh, eoutb, T, tpw, E);

    const int RECV_BLOCKS = 2048;                      // 8192 waves
    const int rpw = (N + RECV_BLOCKS * 4 - 1) / (RECV_BLOCKS * 4);
    k_recv<<<RECV_BLOCKS, BLOCK, 0, stream>>>(xbf, eoutb, cnt2, selfw, bias, out, N, rpw);
}

// Round 11
// 345.154 us; speedup vs baseline: 3.0437x; 1.0784x over previous
//
#include <hip/hip_runtime.h>

#define N_F     64
#define N_REL   32
#define BLOCK   256
#define SCAN_TILE 2048

typedef __attribute__((ext_vector_type(8))) short bf16x8;   // 8 bf16 = 4 VGPRs
typedef __attribute__((ext_vector_type(4))) float f32x4;

__device__ __forceinline__ unsigned short f2bf(float f) {
    unsigned u = __float_as_uint(f);
    u += 0x7FFF + ((u >> 16) & 1);          // RNE
    return (unsigned short)(u >> 16);
}

// ---------------------------------------------------------------------------
// K-pre: region-branched fusion of cast | relw | hist.
// Hist blocks also persist their per-rel histogram to bh[r*nbh + bidh]
// (enables atomic-free pos1 ranking in k_scatter1).
// ---------------------------------------------------------------------------
__global__ void __launch_bounds__(BLOCK) k_pre(const float* __restrict__ nf,
                                               const int* __restrict__ rel,
                                               const int* __restrict__ rcv,
                                               const float* __restrict__ basis,
                                               const float* __restrict__ coeff,
                                               unsigned short* __restrict__ xbf,
                                               unsigned short* __restrict__ Wsh,
                                               int* __restrict__ cnt1,
                                               int* __restrict__ S,    // [0,N): cnt2, [N,..): bh
                                               int E, int total4, int N, int nbh,
                                               int nbCast, int nbRelw) {
    const int bid = blockIdx.x;
    if (bid < nbCast) {
        int i = bid * BLOCK + threadIdx.x;
        if (i < total4) {
            float4 v = ((const float4*)nf)[i];
            ushort4 o;
            o.x = f2bf(v.x); o.y = f2bf(v.y); o.z = f2bf(v.z); o.w = f2bf(v.w);
            ((ushort4*)xbf)[i] = o;
        }
    } else if (bid < nbCast + nbRelw) {
        int idx = (bid - nbCast) * BLOCK + threadIdx.x;
        if (idx < N_REL * N_F * N_F) {
            int r  = idx >> 12;
            int io = idx & 4095;          // k*64 + n
            int k  = io >> 6;
            int n  = io & 63;
            float acc = 0.f;
#pragma unroll
            for (int b = 0; b < 30; ++b)
                acc += coeff[r * 30 + b] * basis[b * (N_F * N_F) + io];
            int ks = k >> 5, kk = k & 31;
            int nt = n >> 4, nl = n & 15;
            int lane = ((kk >> 3) << 4) | nl;
            int j    = kk & 7;
            Wsh[((((r * 2 + ks) * 4 + nt) * 64 + lane) << 3) + j] = f2bf(acc);
        }
    } else {
        __shared__ int h[N_REL];
        if (threadIdx.x < N_REL) h[threadIdx.x] = 0;
        __syncthreads();
        const int bidh = bid - nbCast - nbRelw;
        int e = bidh * BLOCK + threadIdx.x;
        if (e < E) {
            atomicAdd(&h[rel[e]], 1);
            atomicAdd(&S[rcv[e]], 1);          // cnt2
        }
        __syncthreads();
        if (threadIdx.x < N_REL) {
            int v = h[threadIdx.x];
            S[N + threadIdx.x * nbh + bidh] = v;   // bh
            if (v) atomicAdd(&cnt1[threadIdx.x], v);
        }
    }
}

// ---------------------------------------------------------------------------
// Scan stage 1 over the combined array S = [cnt2 | bh]
// ---------------------------------------------------------------------------
__global__ void k_scan_sums(const int* __restrict__ cur, int* __restrict__ part,
                            int nbins) {
    __shared__ int red[BLOCK];
    int base = blockIdx.x * SCAN_TILE;
    int s = 0;
    for (int i = threadIdx.x; i < SCAN_TILE; i += BLOCK) {
        int idx = base + i;
        s += (idx < nbins) ? cur[idx] : 0;
    }
    red[threadIdx.x] = s;
    __syncthreads();
    for (int off = BLOCK / 2; off > 0; off >>= 1) {
        if (threadIdx.x < off) red[threadIdx.x] += red[threadIdx.x + off];
        __syncthreads();
    }
    if (threadIdx.x == 0) part[blockIdx.x] = red[0];
}

// ---------------------------------------------------------------------------
// Single-block middle: scan of tile sums (npart<=256) + rel-bin bases
// (padded base1 AND unpadded ub1) + pad-slot init incl. tail.
// ---------------------------------------------------------------------------
__global__ void k_scan_mid(const int* __restrict__ cnt1, int* __restrict__ base1,
                           int* __restrict__ ub1, int* __restrict__ part,
                           int* __restrict__ esrc, int* __restrict__ perm,
                           int npart, int Ppad) {
    __shared__ int buf[BLOCK];
    __shared__ int sbase[N_REL + 1];
    __shared__ int stotal;
    const int tid = threadIdx.x;

    int v = (tid < npart) ? part[tid] : 0;
    buf[tid] = v;
    __syncthreads();
    for (int off = 1; off < BLOCK; off <<= 1) {
        int t = (tid >= off) ? buf[tid - off] : 0;
        __syncthreads();
        buf[tid] += t;
        __syncthreads();
    }
    if (tid < npart) part[tid] = buf[tid] - v;

    if (tid == 0) {
        int acc = 0, uacc = 0;
        for (int r = 0; r < N_REL; ++r) {
            base1[r] = acc;
            sbase[r] = acc;
            ub1[r]   = uacc;
            acc  += (cnt1[r] + 15) & ~15;
            uacc += cnt1[r];
        }
        base1[N_REL] = Ppad;
        sbase[N_REL] = Ppad;
        ub1[N_REL]   = uacc;
        stotal = acc;                  // actual padded total (<= Ppad)
    }
    __syncthreads();

    // intra-bin pad slots
    for (int i = tid; i < N_REL * 16; i += BLOCK) {
        int r = i >> 4, o = i & 15;
        int c  = cnt1[r];
        int p0 = sbase[r] + c;
        int p1 = sbase[r] + ((c + 15) & ~15);
        int p  = p0 + o;
        if (p < p1) { perm[p] = -1; esrc[p] = 0; }
    }
    // tail [actual_total, Ppad)
    for (int p = stotal + tid; p < Ppad; p += BLOCK) {
        perm[p] = -1; esrc[p] = 0;
    }
}

// ---------------------------------------------------------------------------
// Scan stage 3 over S (+ fused tile->relation table)
// ---------------------------------------------------------------------------
__global__ void k_scan_apply_tile(int* __restrict__ cur, const int* __restrict__ part,
                                  const int* __restrict__ base1,
                                  unsigned char* __restrict__ trel,
                                  int nbins, int npart, int T) {
    if ((int)blockIdx.x >= npart) {
        int t = (blockIdx.x - npart) * BLOCK + threadIdx.x;
        if (t < T) {
            int p = t << 4;
            int r = 0;
#pragma unroll
            for (int i = 1; i < N_REL; ++i) r += (p >= base1[i]);
            trel[t] = (unsigned char)r;
        }
        return;
    }
    __shared__ int buf[BLOCK];
    int base_t = blockIdx.x * SCAN_TILE + threadIdx.x * 8;
    int loc[8];
    int s = 0;
#pragma unroll
    for (int j = 0; j < 8; ++j) {
        int idx = base_t + j;
        int v = (idx < nbins) ? cur[idx] : 0;
        loc[j] = s;
        s += v;
    }
    buf[threadIdx.x] = s;
    __syncthreads();
    for (int off = 1; off < BLOCK; off <<= 1) {
        int t = (threadIdx.x >= off) ? buf[threadIdx.x - off] : 0;
        __syncthreads();
        buf[threadIdx.x] += t;
        __syncthreads();
    }
    int excl = buf[threadIdx.x] - s + part[blockIdx.x];
#pragma unroll
    for (int j = 0; j < 8; ++j) {
        int idx = base_t + j;
        if (idx < nbins) cur[idx] = loc[j] + excl;
    }
}

// ---------------------------------------------------------------------------
// Scatter: pos1 via per-block scanned base + LDS rank (NO global atomics);
// pos2 via mild cur2 atomic (~10 collisions/addr). One barrier.
// S[0,N) = cur2 bases -> end pointers; S[N + r*nbh + b] = scanned bh (+E).
// ---------------------------------------------------------------------------
__global__ void __launch_bounds__(BLOCK) k_scatter1(const int* __restrict__ snd,
                                                    const int* __restrict__ rcv,
                                                    const int* __restrict__ rel,
                                                    int* S,
                                                    const int* __restrict__ base1,
                                                    const int* __restrict__ ub1,
                                                    int* __restrict__ esrc,
                                                    int* __restrict__ perm,
                                                    int E, int N, int nbh) {
    __shared__ int h[N_REL], bhb[N_REL];
    const int b = blockIdx.x;
    if (threadIdx.x < N_REL) {
        int g = S[N + threadIdx.x * nbh + b];              // includes +E offset
        bhb[threadIdx.x] = base1[threadIdx.x] + (g - E - ub1[threadIdx.x]);
        h[threadIdx.x] = 0;
    }
    __syncthreads();
    int e = b * BLOCK + threadIdx.x;
    if (e < E) {
        int r = rel[e];
        int rank = atomicAdd(&h[r], 1);
        int pos1 = bhb[r] + rank;
        int pos2 = atomicAdd(&S[rcv[e]], 1);
        esrc[pos1] = snd[e];
        perm[pos1] = pos2;
    }
}

// ---------------------------------------------------------------------------
// Phase A: per-tile GEMM -> bf16 edge rows at receiver-sorted positions.
// 1-deep prefetch of next tile's esrc/perm. No barriers/atomics.
// ---------------------------------------------------------------------------
__global__ void __launch_bounds__(BLOCK) k_gemm(const unsigned short* __restrict__ xbf,
                                                const int* __restrict__ esrc,
                                                const int* __restrict__ perm,
                                                const unsigned char* __restrict__ trel,
                                                const unsigned short* __restrict__ Wsh,
                                                unsigned short* __restrict__ eoutb,
                                                int T, int tpw, int dumprow) {
    __shared__ float ts[4][16 * 68];        // per-wave 16x64 transpose, stride 68
    const int tid  = threadIdx.x;
    const int lane = tid & 63;
    const int wave = tid >> 6;
    float* tb = ts[wave];

    const int gw = blockIdx.x * 4 + wave;
    const int t0 = gw * tpw;
    const int t1 = min(t0 + tpw, T);
    if (t0 >= T) return;

    const int row = lane & 15;
    const int kg  = lane >> 4;
    const int rr  = lane >> 2;      // store-phase row
    const int ch  = lane & 3;       // store-phase 16-col chunk

    int curR = -1;
    bf16x8 wf[2][4];

    int s_cur  = esrc[(t0 << 4) + row];
    int pm_cur = perm[(t0 << 4) + row];

    for (int t = t0; t < t1; ++t) {
        int s_nxt = 0, pm_nxt = -1;
        if (t + 1 < t1) {
            s_nxt  = esrc[((t + 1) << 4) + row];
            pm_nxt = perm[((t + 1) << 4) + row];
        }

        const int r = trel[t];
        if (r != curR) {
            curR = r;
#pragma unroll
            for (int ks = 0; ks < 2; ++ks)
#pragma unroll
                for (int nt = 0; nt < 4; ++nt)
                    wf[ks][nt] = *(const bf16x8*)(Wsh + ((((r * 2 + ks) * 4 + nt) * 64 + lane) << 3));
        }

        const size_t xb = ((size_t)s_cur << 6) + (kg << 3);
        bf16x8 a0 = *(const bf16x8*)(xbf + xb);
        bf16x8 a1 = *(const bf16x8*)(xbf + xb + 32);

        f32x4 acc[4];
#pragma unroll
        for (int nt = 0; nt < 4; ++nt) {
            acc[nt] = (f32x4){0.f, 0.f, 0.f, 0.f};
            acc[nt] = __builtin_amdgcn_mfma_f32_16x16x32_bf16(a0, wf[0][nt], acc[nt], 0, 0, 0);
            acc[nt] = __builtin_amdgcn_mfma_f32_16x16x32_bf16(a1, wf[1][nt], acc[nt], 0, 0, 0);
        }

        // C-layout (col=lane&15, row=kg*4+reg) -> LDS row-major
#pragma unroll
        for (int nt = 0; nt < 4; ++nt)
#pragma unroll
            for (int reg = 0; reg < 4; ++reg)
                tb[(kg * 4 + reg) * 68 + nt * 16 + (lane & 15)] = acc[nt][reg];

        asm volatile("s_waitcnt lgkmcnt(0)" ::: "memory");   // wave-local RAW

        int pmr = __shfl(pm_cur, rr);         // dest row of store-phase row
        pmr = (pmr < 0) ? dumprow : pmr;      // pad rows -> dump

        const float* src = tb + rr * 68 + ch * 16;
        unsigned pk[8];
#pragma unroll
        for (int q = 0; q < 4; ++q) {
            float4 v = *(const float4*)(src + q * 4);
            pk[2 * q]     = (unsigned)f2bf(v.x) | ((unsigned)f2bf(v.y) << 16);
            pk[2 * q + 1] = (unsigned)f2bf(v.z) | ((unsigned)f2bf(v.w) << 16);
        }
        unsigned short* dst = eoutb + (size_t)pmr * 64 + ch * 16;
        uint4 v0; v0.x = pk[0]; v0.y = pk[1]; v0.z = pk[2]; v0.w = pk[3];
        uint4 v1; v1.x = pk[4]; v1.y = pk[5]; v1.z = pk[6]; v1.w = pk[7];
        *(uint4*)dst       = v0;
        *(uint4*)(dst + 8) = v1;

        s_cur = s_nxt; pm_cur = pm_nxt;
    }
}

// ---------------------------------------------------------------------------
// Phase B: wave per node. 2-rows-per-load (g = lane>>5, c = lane&31; one
// dword = 2 bf16, 256 B/wave-load). Reduction = 1 shfl_xor + 2 shfls +
// select. Span boundaries prefetched. bf16 self-loop. No atomics/LDS.
// ---------------------------------------------------------------------------
__global__ void __launch_bounds__(BLOCK) k_recv(const unsigned short* __restrict__ xbf,
                                                const unsigned short* __restrict__ eoutb,
                                                const int* __restrict__ cur2,
                                                const float* __restrict__ selfw,
                                                const float* __restrict__ bias,
                                                float* __restrict__ out,
                                                int N, int rpw) {
    const int tid  = threadIdx.x;
    const int lane = tid & 63;
    const int wave = tid >> 6;
    const int gw   = blockIdx.x * 4 + wave;
    const int n0   = gw * rpw;
    const int n1   = min(n0 + rpw, N);
    if (n0 >= N) return;

    const int g = lane >> 5;        // row parity
    const int c = lane & 31;        // feat-pair index (feats 2c, 2c+1)

    float swcol[N_F];
#pragma unroll
    for (int i = 0; i < N_F; ++i) swcol[i] = selfw[i * N_F + lane];
    const float bv = bias[lane];

    // prefetch span boundaries: lane l holds cur2[n0-1+l]
    int bidx = n0 - 1 + lane;
    int bnd  = 0;
    if (bidx >= 0 && bidx < N && lane <= (n1 - n0)) bnd = cur2[bidx];

    for (int n = n0; n < n1; ++n) {
        const int li = n - n0;
        const int st = __shfl(bnd, li);
        const int en = __shfl(bnd, li + 1);

        float a0 = 0.f, a1 = 0.f;
        int j = st;
        for (; j + 4 <= en; j += 4) {
            unsigned u0 = *(const unsigned*)(eoutb + ((size_t)(j + g)     << 6) + (c << 1));
            unsigned u1 = *(const unsigned*)(eoutb + ((size_t)(j + 2 + g) << 6) + (c << 1));
            a0 += __uint_as_float(u0 << 16) + __uint_as_float(u1 << 16);
            a1 += __uint_as_float(u0 & 0xFFFF0000u) + __uint_as_float(u1 & 0xFFFF0000u);
        }
        for (; j < en; j += 2) {
            int row = j + g;        // overread row <= en < Ppad: safe, masked
            unsigned u = *(const unsigned*)(eoutb + ((size_t)row << 6) + (c << 1));
            if (row < en) {
                a0 += __uint_as_float(u << 16);
                a1 += __uint_as_float(u & 0xFFFF0000u);
            }
        }
        a0 += __shfl_xor(a0, 32);
        a1 += __shfl_xor(a1, 32);
        float v0 = __shfl(a0, lane >> 1);
        float v1 = __shfl(a1, lane >> 1);
        float agg = (lane & 1) ? v1 : v0;

        // self-loop from bf16 x (broadcast uint4 = 8 feats)
        const uint4* xr = (const uint4*)(xbf + ((size_t)n << 6));
        float s0 = 0.f, s1 = 0.f, s2 = 0.f, s3 = 0.f;
#pragma unroll
        for (int q = 0; q < 8; ++q) {
            uint4 u = xr[q];
            float x0 = __uint_as_float(u.x << 16);
            float x1 = __uint_as_float(u.x & 0xFFFF0000u);
            float x2 = __uint_as_float(u.y << 16);
            float x3 = __uint_as_float(u.y & 0xFFFF0000u);
            float x4 = __uint_as_float(u.z << 16);
            float x5 = __uint_as_float(u.z & 0xFFFF0000u);
            float x6 = __uint_as_float(u.w << 16);
            float x7 = __uint_as_float(u.w & 0xFFFF0000u);
            s0 = __builtin_fmaf(x0, swcol[8 * q + 0], s0);
            s1 = __builtin_fmaf(x1, swcol[8 * q + 1], s1);
            s2 = __builtin_fmaf(x2, swcol[8 * q + 2], s2);
            s3 = __builtin_fmaf(x3, swcol[8 * q + 3], s3);
            s0 = __builtin_fmaf(x4, swcol[8 * q + 4], s0);
            s1 = __builtin_fmaf(x5, swcol[8 * q + 5], s1);
            s2 = __builtin_fmaf(x6, swcol[8 * q + 6], s2);
            s3 = __builtin_fmaf(x7, swcol[8 * q + 7], s3);
        }

        float dg  = (float)(en - st);
        float inv = 1.f / (dg < 1.f ? 1.f : dg);
        out[(size_t)n * N_F + lane] = agg * inv + (s0 + s1) + (s2 + s3) + bv;
    }
}

// ---------------------------------------------------------------------------
extern "C" void kernel_launch(void* const* d_in, const int* in_sizes, int n_in,
                              void* d_out, int out_size, void* d_ws, size_t ws_size,
                              hipStream_t stream) {
    const float* nf    = (const float*)d_in[0];
    const int*   snd   = (const int*)  d_in[1];
    const int*   rcv   = (const int*)  d_in[2];
    const int*   rel   = (const int*)  d_in[3];
    const float* basis = (const float*)d_in[4];
    const float* coeff = (const float*)d_in[5];
    const float* selfw = (const float*)d_in[6];
    const float* bias  = (const float*)d_in[7];
    float*       out   = (float*)d_out;

    const int N = in_sizes[0] / N_F;                  // 100000
    const int E = in_sizes[1];                        // 1000000
    const int Ppad = (E + N_REL * 15 + 15) & ~15;     // padded rel-sorted length
    const int T    = Ppad >> 4;                       // total 16-edge tiles
    const int total4 = N * N_F / 4;

    const int NB_CAST = (total4 + BLOCK - 1) / BLOCK;
    const int NB_RELW = (N_REL * N_F * N_F + BLOCK - 1) / BLOCK;
    const int NB_HIST = (E + BLOCK - 1) / BLOCK;      // == nbh
    const int nbh     = NB_HIST;

    const int SCAN_N = N + N_REL * nbh;               // combined scan length
    const int NPART  = (SCAN_N + SCAN_TILE - 1) / SCAN_TILE;   // <= 256

    // ws layout
    unsigned short* eoutb = (unsigned short*)d_ws;                    // Ppad*64 bf16
    unsigned short* Wsh   = eoutb + (size_t)Ppad * N_F;               // 131072
    unsigned short* xbf   = Wsh + (size_t)N_REL * N_F * N_F;          // N*64
    int* base1 = (int*)(xbf + (size_t)N * N_F);                       // 64
    int* ub1   = base1 + 64;                                          // 64
    int* part  = ub1 + 64;                                            // 256
    int* cnt1  = part + 256;                                          // 32     } one memset
    int* S     = cnt1 + 32;                                           // SCAN_N }
    int* esrc  = S + SCAN_N;                                          // Ppad
    int* perm  = esrc + Ppad;                                         // Ppad
    unsigned char* trel = (unsigned char*)(perm + Ppad);              // T

    hipMemsetAsync(cnt1, 0, (size_t)(32 + SCAN_N) * sizeof(int), stream);

    k_pre<<<NB_CAST + NB_RELW + NB_HIST, BLOCK, 0, stream>>>(
        nf, rel, rcv, basis, coeff, xbf, Wsh, cnt1, S, E, total4, N, nbh, NB_CAST, NB_RELW);

    k_scan_sums<<<NPART, BLOCK, 0, stream>>>(S, part, SCAN_N);
    k_scan_mid <<<1,     BLOCK, 0, stream>>>(cnt1, base1, ub1, part, esrc, perm, NPART, Ppad);

    const int NB_TREL = (T + BLOCK - 1) / BLOCK;
    k_scan_apply_tile<<<NPART + NB_TREL, BLOCK, 0, stream>>>(S, part, base1, trel,
                                                             SCAN_N, NPART, T);

    k_scatter1<<<nbh, BLOCK, 0, stream>>>(snd, rcv, rel, S, base1, ub1, esrc, perm,
                                          E, N, nbh);

    const int GEMM_BLOCKS = 2048;                      // 8192 waves
    const int tpw = (T + GEMM_BLOCKS * 4 - 1) / (GEMM_BLOCKS * 4);
    k_gemm<<<GEMM_BLOCKS, BLOCK, 0, stream>>>(xbf, esrc, perm, trel, Wsh, eoutb, T, tpw, E);

    const int RECV_BLOCKS = 4096;                      // 16384 waves
    const int rpw = (N + RECV_BLOCKS * 4 - 1) / (RECV_BLOCKS * 4);
    k_recv<<<RECV_BLOCKS, BLOCK, 0, stream>>>(xbf, eoutb, S, selfw, bias, out, N, rpw);
}